// Round 4
// baseline (927.234 us; speedup 1.0000x reference)
//
#include <hip/hip_runtime.h>
#include <math.h>

#define M_TOK 8192
#define D_DIM 2048
#define G_GENES 4096
#define GD_DIM 256
#define KSEL 32
#define NCAND 40

typedef float f32x4 __attribute__((ext_vector_type(4)));
typedef short bf16x8 __attribute__((ext_vector_type(8)));

__device__ __forceinline__ void async_copy16(const void* g, void* lds) {
  __builtin_amdgcn_global_load_lds((const __attribute__((address_space(1))) void*)g,
                                   (__attribute__((address_space(3))) void*)lds, 16, 0, 0);
}

__device__ __forceinline__ unsigned short f2bf(float f) {
  unsigned int u = __float_as_uint(f);
  unsigned int r = (u + 0x7fffu + ((u >> 16) & 1u)) >> 16;
  return (unsigned short)r;
}
__device__ __forceinline__ float bf2f(unsigned short h) {
  return __uint_as_float(((unsigned int)h) << 16);
}

// ---------------- K1: RMSNorm -> r[t], xn_bf16 ----------------
__global__ __launch_bounds__(256) void k1_rmsnorm(const float* __restrict__ x,
                                                  const float* __restrict__ nw,
                                                  float* __restrict__ r_out,
                                                  unsigned short* __restrict__ xn_bf) {
  int t = blockIdx.x, tid = threadIdx.x;
  const float4* xr = (const float4*)(x + (size_t)t * D_DIM);
  float4 a = xr[tid], b = xr[tid + 256];
  double ss = (double)a.x*a.x + (double)a.y*a.y + (double)a.z*a.z + (double)a.w*a.w
            + (double)b.x*b.x + (double)b.y*b.y + (double)b.z*b.z + (double)b.w*b.w;
  for (int off = 32; off; off >>= 1) ss += __shfl_down(ss, off);
  __shared__ double sred[4];
  __shared__ float rshare;
  int lane = tid & 63, wv = tid >> 6;
  if (lane == 0) sred[wv] = ss;
  __syncthreads();
  if (tid == 0) {
    double tot = sred[0] + sred[1] + sred[2] + sred[3];
    float r = (float)(1.0 / sqrt(tot / (double)D_DIM + 1.1920928955078125e-7));
    rshare = r; r_out[t] = r;
  }
  __syncthreads();
  float r = rshare;
  const float4* nw4 = (const float4*)nw;
  float4 na = nw4[tid], nb = nw4[tid + 256];
  ushort4 oa, ob;
  oa.x = f2bf(a.x * r * na.x); oa.y = f2bf(a.y * r * na.y);
  oa.z = f2bf(a.z * r * na.z); oa.w = f2bf(a.w * r * na.w);
  ob.x = f2bf(b.x * r * nb.x); ob.y = f2bf(b.y * r * nb.y);
  ob.z = f2bf(b.z * r * nb.z); ob.w = f2bf(b.w * r * nb.w);
  ushort4* o4 = (ushort4*)(xn_bf + (size_t)t * D_DIM);
  o4[tid] = oa; o4[tid + 256] = ob;
}

// ---------------- K2: Wc fp32 -> bf16 ----------------
__global__ __launch_bounds__(256) void k2_cvt(const float* __restrict__ w,
                                              unsigned short* __restrict__ wb) {
  size_t i = (size_t)blockIdx.x * 256 + threadIdx.x;   // handles 8 elements
  const float4* w4 = (const float4*)w;
  float4 a = w4[2*i], b = w4[2*i+1];
  ushort4 oa, ob;
  oa.x = f2bf(a.x); oa.y = f2bf(a.y); oa.z = f2bf(a.z); oa.w = f2bf(a.w);
  ob.x = f2bf(b.x); ob.y = f2bf(b.y); ob.z = f2bf(b.z); ob.w = f2bf(b.w);
  ((ushort4*)wb)[2*i] = oa; ((ushort4*)wb)[2*i+1] = ob;
}

// ---------------- K2b: split Wd/Wu into bf16 hi+lo ----------------
__global__ __launch_bounds__(256) void k2b_split(const float* __restrict__ wd,
                                                 const float* __restrict__ wu,
                                                 unsigned short* __restrict__ wdh,
                                                 unsigned short* __restrict__ wdl,
                                                 unsigned short* __restrict__ wuh,
                                                 unsigned short* __restrict__ wul) {
  const float* src = blockIdx.y ? wu : wd;
  unsigned short* dh = blockIdx.y ? wuh : wdh;
  unsigned short* dl = blockIdx.y ? wul : wdl;
  size_t i = (size_t)blockIdx.x * 256 + threadIdx.x;   // float4 index
  float4 v = ((const float4*)src)[i];
  ushort4 h, l;
  h.x = f2bf(v.x); l.x = f2bf(v.x - bf2f(h.x));
  h.y = f2bf(v.y); l.y = f2bf(v.y - bf2f(h.y));
  h.z = f2bf(v.z); l.z = f2bf(v.z - bf2f(h.z));
  h.w = f2bf(v.w); l.w = f2bf(v.w - bf2f(h.w));
  ((ushort4*)dh)[i] = h;
  ((ushort4*)dl)[i] = l;
}

// ---------------- K3: approx logits GEMM (bf16 MFMA, 128x128 tile) ----------------
__global__ __launch_bounds__(256) void k3_gemm_logits(const unsigned short* __restrict__ A,
                                                      const unsigned short* __restrict__ B,
                                                      unsigned short* __restrict__ C) {
  __shared__ unsigned short As[128 * 32];
  __shared__ unsigned short Bs[128 * 32];
  int tid = threadIdx.x;
  int lane = tid & 63, wv = tid >> 6;
  // bijective XCD swizzle over 2048 blocks (2048 % 8 == 0)
  int lin = blockIdx.y * gridDim.x + blockIdx.x;
  int swz = (lin & 7) * (2048 / 8) + (lin >> 3);
  int bn = swz & 31, bm = swz >> 5;
  int wr = wv >> 1, wc = wv & 1;
  f32x4 acc[4][4];
#pragma unroll
  for (int m = 0; m < 4; ++m)
#pragma unroll
    for (int n = 0; n < 4; ++n) acc[m][n] = (f32x4){0.f, 0.f, 0.f, 0.f};

  const int lrow = lane >> 2;
  const int lcol = (lane & 3) * 8;
  size_t abase = (size_t)(bm * 128) * D_DIM;
  size_t bbase = (size_t)(bn * 128) * D_DIM;

  for (int kt = 0; kt < D_DIM; kt += 32) {
    __syncthreads();
#pragma unroll
    for (int c = 0; c < 2; ++c) {
      int rr = (wv * 2 + c) * 16 + lrow;
      async_copy16(A + abase + (size_t)rr * D_DIM + kt + lcol, &As[(wv * 2 + c) * 512]);
      async_copy16(B + bbase + (size_t)rr * D_DIM + kt + lcol, &Bs[(wv * 2 + c) * 512]);
    }
    __syncthreads();
    bf16x8 fa[4], fb[4];
#pragma unroll
    for (int m = 0; m < 4; ++m)
      fa[m] = *(const bf16x8*)&As[(wr * 64 + m * 16 + (lane & 15)) * 32 + (lane >> 4) * 8];
#pragma unroll
    for (int n = 0; n < 4; ++n)
      fb[n] = *(const bf16x8*)&Bs[(wc * 64 + n * 16 + (lane & 15)) * 32 + (lane >> 4) * 8];
#pragma unroll
    for (int m = 0; m < 4; ++m)
#pragma unroll
      for (int n = 0; n < 4; ++n)
        acc[m][n] = __builtin_amdgcn_mfma_f32_16x16x32_bf16(fa[m], fb[n], acc[m][n], 0, 0, 0);
  }
#pragma unroll
  for (int m = 0; m < 4; ++m)
#pragma unroll
    for (int n = 0; n < 4; ++n)
#pragma unroll
      for (int j = 0; j < 4; ++j) {
        int row = bm * 128 + wr * 64 + m * 16 + (lane >> 4) * 4 + j;
        int col = bn * 128 + wc * 64 + n * 16 + (lane & 15);
        C[(size_t)row * G_GENES + col] = f2bf(acc[m][n][j]);
      }
}

// ---------------- K4: per-token top-40 candidates (1 wave / token) ----------------
__global__ __launch_bounds__(256) void k4_topk(const unsigned short* __restrict__ L,
                                               int* __restrict__ cand) {
  int wv = threadIdx.x >> 6, lane = threadIdx.x & 63;
  int t = blockIdx.x * 4 + wv;
  const unsigned short* lp = L + (size_t)t * G_GENES;
  float v[64];
#pragma unroll
  for (int i = 0; i < 8; ++i) {
    uint4 raw = *(const uint4*)(lp + i * 512 + lane * 8);
    v[i*8+0] = __uint_as_float(raw.x << 16);
    v[i*8+1] = __uint_as_float(raw.x & 0xffff0000u);
    v[i*8+2] = __uint_as_float(raw.y << 16);
    v[i*8+3] = __uint_as_float(raw.y & 0xffff0000u);
    v[i*8+4] = __uint_as_float(raw.z << 16);
    v[i*8+5] = __uint_as_float(raw.z & 0xffff0000u);
    v[i*8+6] = __uint_as_float(raw.w << 16);
    v[i*8+7] = __uint_as_float(raw.w & 0xffff0000u);
  }
  unsigned long long alive = ~0ull;
  for (int it = 0; it < NCAND; ++it) {
    float best = -3.0e38f; int bslot = 0;
#pragma unroll
    for (int s = 0; s < 64; ++s) {
      bool ok = (alive >> s) & 1ull;
      if (ok && v[s] > best) { best = v[s]; bslot = s; }
    }
    unsigned int g = ((unsigned)(bslot >> 3)) * 512u + (unsigned)lane * 8u + (unsigned)(bslot & 7);
    float m = best; unsigned int mg = g;
#pragma unroll
    for (int off = 32; off; off >>= 1) {
      float om = __shfl_xor(m, off);
      unsigned int og = __shfl_xor(mg, off);
      if (om > m || (om == m && og < mg)) { m = om; mg = og; }
    }
    if (lane == (int)((mg >> 3) & 63u)) {
      int s = (int)(((mg >> 9) << 3) | (mg & 7u));
      alive &= ~(1ull << s);
    }
    if (lane == 0) cand[(size_t)t * NCAND + it] = (int)mg;
  }
}

// ---------------- K5: exact fp64 rescore, gene-sliced for L2 residency ----------------
// slice = blockIdx.x & 7 rides round-robin block->XCD dispatch: all blocks with
// slice s land on XCD s, whose 4 MB L2 exactly holds Wc rows [s*512,(s+1)*512).
// Each block: 8 tokens (4 waves x 2), processing only candidates in its slice
// (ballot-compacted, ~5/token). Per-candidate fp64 math identical to R2/R3.
__global__ __launch_bounds__(256) void k5_rescore(const float* __restrict__ x,
                                                  const float* __restrict__ r,
                                                  const float* __restrict__ nw,
                                                  const float* __restrict__ Wc,
                                                  const float* __restrict__ temp,
                                                  const int* __restrict__ cand,
                                                  double* __restrict__ cval) {
  int bid = blockIdx.x;
  int slice = bid & 7;
  int group = bid >> 3;
  int wv = threadIdx.x >> 6, lane = threadIdx.x & 63;
  float tclamp = fmaxf(temp[0], 0.1f);
  const float4* nw4 = (const float4*)nw;
  float4 nv[8];
#pragma unroll
  for (int i = 0; i < 8; ++i) nv[i] = nw4[i * 64 + lane];
#pragma unroll 1
  for (int tt = 0; tt < 2; ++tt) {
    int t = group * 8 + wv * 2 + tt;
    float rr = r[t];
    const float4* x4 = (const float4*)(x + (size_t)t * D_DIM);
    float4 xl[8];
#pragma unroll
    for (int i = 0; i < 8; ++i) {
      float4 xv = x4[i * 64 + lane];
      xl[i].x = xv.x * rr * nv[i].x;
      xl[i].y = xv.y * rr * nv[i].y;
      xl[i].z = xv.z * rr * nv[i].z;
      xl[i].w = xv.w * rr * nv[i].w;
    }
    const int base = t * NCAND;
    int myg = cand[base + (lane < NCAND ? lane : 0)];
    unsigned long long mask = __ballot((lane < NCAND) && ((myg >> 9) == slice));
#pragma unroll 1
    while (mask) {
      int j = __ffsll((unsigned long long)mask) - 1;
      mask &= mask - 1;
      int g = __shfl(myg, j);
      const float4* w4 = (const float4*)(Wc + (size_t)g * D_DIM);
      double a0 = 0, a1 = 0, a2 = 0, a3 = 0;
#pragma unroll
      for (int i = 0; i < 8; ++i) {
        float4 w = w4[i * 64 + lane];
        a0 += (double)xl[i].x * (double)w.x;
        a1 += (double)xl[i].y * (double)w.y;
        a2 += (double)xl[i].z * (double)w.z;
        a3 += (double)xl[i].w * (double)w.w;
      }
      double acc = (a0 + a1) + (a2 + a3);
#pragma unroll
      for (int off = 32; off; off >>= 1) acc += __shfl_down(acc, off);
      if (lane == 0) cval[base + j] = acc / (double)tclamp;
    }
  }
}

// ---------------- K6: select top-32, softmax, combine -> expressed (bf16 hi/lo) ----------------
__global__ __launch_bounds__(256) void k6_express(const double* __restrict__ cval,
                                                  const int* __restrict__ cand,
                                                  const float* __restrict__ genes,
                                                  unsigned short* __restrict__ e_hi,
                                                  unsigned short* __restrict__ e_lo) {
  int t = blockIdx.x, tid = threadIdx.x;
  __shared__ double sval[NCAND];
  __shared__ int sidx[NCAND];
  __shared__ float sw[NCAND];
  if (tid < NCAND) {
    sval[tid] = cval[(size_t)t * NCAND + tid];
    sidx[tid] = cand[(size_t)t * NCAND + tid];
  }
  __syncthreads();
  if (tid < 64) {
    double v = (tid < NCAND) ? sval[tid] : -1.0e300;
    int gi = (tid < NCAND) ? sidx[tid] : 0x7fffffff;
    int rank = 0;
    for (int j = 0; j < NCAND; ++j) {
      double vj = sval[j]; int gj = sidx[j];
      if (vj > v || (vj == v && gj < gi)) rank++;
    }
    bool sel = (tid < NCAND) && (rank < KSEL);
    double vs = sel ? v : -1.0e300;
    double mx = vs;
    for (int off = 32; off; off >>= 1) { double o = __shfl_xor(mx, off); mx = fmax(mx, o); }
    double e = sel ? exp(v - mx) : 0.0;
    double ssum = e;
    for (int off = 32; off; off >>= 1) ssum += __shfl_xor(ssum, off);
    if (tid < NCAND) sw[tid] = (float)(e / ssum);
  }
  __syncthreads();
  float a0 = 0.f, a1 = 0.f, a2 = 0.f, a3 = 0.f;
#pragma unroll
  for (int k = 0; k < NCAND; k += 4) {
    a0 += sw[k]     * genes[(size_t)sidx[k]     * GD_DIM + tid];
    a1 += sw[k + 1] * genes[(size_t)sidx[k + 1] * GD_DIM + tid];
    a2 += sw[k + 2] * genes[(size_t)sidx[k + 2] * GD_DIM + tid];
    a3 += sw[k + 3] * genes[(size_t)sidx[k + 3] * GD_DIM + tid];
  }
  float acc = (a0 + a1) + (a2 + a3);
  unsigned short h = f2bf(acc);
  unsigned short l = f2bf(acc - bf2f(h));
  e_hi[(size_t)t * GD_DIM + tid] = h;
  e_lo[(size_t)t * GD_DIM + tid] = l;
}

// ---------------- K7: bf16-split MFMA down/up GEMM + tanh + xn + scale -> out ----------------
// A = expressed [M][256] (hi/lo), B = Wd/Wu [2048][256] (hi/lo). Tile 128(M) x 64(N), BK=32.
__global__ __launch_bounds__(256) void k7_mfma(const unsigned short* __restrict__ e_hi,
                                               const unsigned short* __restrict__ e_lo,
                                               const unsigned short* __restrict__ wdh,
                                               const unsigned short* __restrict__ wdl,
                                               const unsigned short* __restrict__ wuh,
                                               const unsigned short* __restrict__ wul,
                                               const float* __restrict__ x,
                                               const float* __restrict__ r,
                                               const float* __restrict__ nw,
                                               const float* __restrict__ scale_p,
                                               float* __restrict__ out) {
  __shared__ unsigned short Ah[128 * 32], Al[128 * 32];
  __shared__ unsigned short Dh[64 * 32], Dl[64 * 32], Uh[64 * 32], Ul[64 * 32];
  int tid = threadIdx.x;
  int lane = tid & 63, wv = tid >> 6;
  int bn = blockIdx.x, bm = blockIdx.y;
  int wr = wv >> 1, wc = wv & 1;   // wave tile: 64(M) x 32(N)
  const int lrow = lane >> 2;
  const int lcol = (lane & 3) * 8;

  f32x4 accD[4][2], accU[4][2];
#pragma unroll
  for (int m = 0; m < 4; ++m)
#pragma unroll
    for (int n = 0; n < 2; ++n) {
      accD[m][n] = (f32x4){0.f, 0.f, 0.f, 0.f};
      accU[m][n] = (f32x4){0.f, 0.f, 0.f, 0.f};
    }

  for (int kt = 0; kt < GD_DIM; kt += 32) {
    __syncthreads();
#pragma unroll
    for (int c = 0; c < 8; ++c) {
      int cid = wv * 8 + c;
      if (cid < 8) {
        async_copy16(e_hi + (size_t)(bm * 128 + cid * 16 + lrow) * GD_DIM + kt + lcol,
                     &Ah[cid * 512]);
      } else if (cid < 16) {
        int cc = cid - 8;
        async_copy16(e_lo + (size_t)(bm * 128 + cc * 16 + lrow) * GD_DIM + kt + lcol,
                     &Al[cc * 512]);
      } else if (cid < 20) {
        int cc = cid - 16;
        async_copy16(wdh + (size_t)(bn * 64 + cc * 16 + lrow) * GD_DIM + kt + lcol,
                     &Dh[cc * 512]);
      } else if (cid < 24) {
        int cc = cid - 20;
        async_copy16(wdl + (size_t)(bn * 64 + cc * 16 + lrow) * GD_DIM + kt + lcol,
                     &Dl[cc * 512]);
      } else if (cid < 28) {
        int cc = cid - 24;
        async_copy16(wuh + (size_t)(bn * 64 + cc * 16 + lrow) * GD_DIM + kt + lcol,
                     &Uh[cc * 512]);
      } else {
        int cc = cid - 28;
        async_copy16(wul + (size_t)(bn * 64 + cc * 16 + lrow) * GD_DIM + kt + lcol,
                     &Ul[cc * 512]);
      }
    }
    __syncthreads();
    bf16x8 fah[4], fal[4], fdh[2], fdl[2], fuh[2], ful[2];
#pragma unroll
    for (int m = 0; m < 4; ++m) {
      int off = (wr * 64 + m * 16 + (lane & 15)) * 32 + (lane >> 4) * 8;
      fah[m] = *(const bf16x8*)&Ah[off];
      fal[m] = *(const bf16x8*)&Al[off];
    }
#pragma unroll
    for (int n = 0; n < 2; ++n) {
      int off = (wc * 32 + n * 16 + (lane & 15)) * 32 + (lane >> 4) * 8;
      fdh[n] = *(const bf16x8*)&Dh[off];
      fdl[n] = *(const bf16x8*)&Dl[off];
      fuh[n] = *(const bf16x8*)&Uh[off];
      ful[n] = *(const bf16x8*)&Ul[off];
    }
#pragma unroll
    for (int m = 0; m < 4; ++m)
#pragma unroll
      for (int n = 0; n < 2; ++n) {
        accD[m][n] = __builtin_amdgcn_mfma_f32_16x16x32_bf16(fah[m], fdh[n], accD[m][n], 0, 0, 0);
        accD[m][n] = __builtin_amdgcn_mfma_f32_16x16x32_bf16(fah[m], fdl[n], accD[m][n], 0, 0, 0);
        accD[m][n] = __builtin_amdgcn_mfma_f32_16x16x32_bf16(fal[m], fdh[n], accD[m][n], 0, 0, 0);
        accU[m][n] = __builtin_amdgcn_mfma_f32_16x16x32_bf16(fah[m], fuh[n], accU[m][n], 0, 0, 0);
        accU[m][n] = __builtin_amdgcn_mfma_f32_16x16x32_bf16(fah[m], ful[n], accU[m][n], 0, 0, 0);
        accU[m][n] = __builtin_amdgcn_mfma_f32_16x16x32_bf16(fal[m], fuh[n], accU[m][n], 0, 0, 0);
      }
  }
  float sc = scale_p[0];
#pragma unroll
  for (int m = 0; m < 4; ++m)
#pragma unroll
    for (int j = 0; j < 4; ++j) {
      int token = bm * 128 + wr * 64 + m * 16 + (lane >> 4) * 4 + j;
      float rr = r[token];
#pragma unroll
      for (int n = 0; n < 2; ++n) {
        int d = bn * 64 + wc * 32 + n * 16 + (lane & 15);
        float xn = x[(size_t)token * D_DIM + d] * rr * nw[d];
        out[(size_t)token * D_DIM + d] = tanhf(accD[m][n][j]) * xn * accU[m][n][j] * sc;
      }
    }
}

extern "C" void kernel_launch(void* const* d_in, const int* in_sizes, int n_in,
                              void* d_out, int out_size, void* d_ws, size_t ws_size,
                              hipStream_t stream) {
  const float* x       = (const float*)d_in[0];
  const float* Wc      = (const float*)d_in[1];
  const float* temp    = (const float*)d_in[2];
  const float* genes   = (const float*)d_in[3];
  const float* Wd      = (const float*)d_in[4];
  const float* Wu      = (const float*)d_in[5];
  const float* nw      = (const float*)d_in[6];
  const float* scale_p = (const float*)d_in[7];

  char* ws = (char*)d_ws;
  float* r_buf          = (float*)ws;                                   // 32 KB (64 KB reserved)
  unsigned short* xn_bf = (unsigned short*)(ws + 65536);                // 32 MB (free after k3)
  unsigned short* wc_bf = (unsigned short*)(ws + 65536 + (size_t)M_TOK * D_DIM * 2);   // 16 MB
  char* p = ws + 65536 + (size_t)M_TOK * D_DIM * 2 + (size_t)G_GENES * D_DIM * 2;
  int* cand    = (int*)p;                       p += (size_t)M_TOK * NCAND * 4;
  double* cval = (double*)p;                    p += (size_t)M_TOK * NCAND * 8;
  unsigned short* e_hi = (unsigned short*)p;    p += (size_t)M_TOK * GD_DIM * 2;
  unsigned short* e_lo = (unsigned short*)p;

  // Wd/Wu bf16 hi/lo splits live in the xn_bf region (dead after k3): 4 x 1 MB
  unsigned short* wdh = (unsigned short*)(ws + 65536);
  unsigned short* wdl = wdh + (size_t)D_DIM * GD_DIM;
  unsigned short* wuh = wdl + (size_t)D_DIM * GD_DIM;
  unsigned short* wul = wuh + (size_t)D_DIM * GD_DIM;

  unsigned short* logits_bf = (unsigned short*)d_out;  // 33.5M bf16 == 64 MB == d_out

  k1_rmsnorm<<<dim3(M_TOK), dim3(256), 0, stream>>>(x, nw, r_buf, xn_bf);
  k2_cvt<<<dim3((G_GENES * D_DIM) / (256 * 8)), dim3(256), 0, stream>>>(Wc, wc_bf);
  k3_gemm_logits<<<dim3(G_GENES / 128, M_TOK / 128), dim3(256), 0, stream>>>(xn_bf, wc_bf, logits_bf);
  k4_topk<<<dim3(M_TOK / 4), dim3(256), 0, stream>>>(logits_bf, cand);
  k2b_split<<<dim3((D_DIM * GD_DIM) / (256 * 4), 2), dim3(256), 0, stream>>>(Wd, Wu, wdh, wdl, wuh, wul);
  k5_rescore<<<dim3(M_TOK), dim3(256), 0, stream>>>(x, r_buf, nw, Wc, temp, cand, cval);
  k6_express<<<dim3(M_TOK), dim3(256), 0, stream>>>(cval, cand, genes, e_hi, e_lo);
  k7_mfma<<<dim3(D_DIM / 64, M_TOK / 128), dim3(256), 0, stream>>>(e_hi, e_lo, wdh, wdl, wuh, wul,
                                                                   x, r_buf, nw, scale_p, (float*)d_out);
}

// Round 5
// 918.597 us; speedup vs baseline: 1.0094x; 1.0094x over previous
//
#include <hip/hip_runtime.h>
#include <math.h>

#define M_TOK 8192
#define D_DIM 2048
#define G_GENES 4096
#define GD_DIM 256
#define KSEL 32
#define NCAND 40
#define NSLICE 8

typedef float f32x4 __attribute__((ext_vector_type(4)));
typedef short bf16x8 __attribute__((ext_vector_type(8)));

__device__ __forceinline__ void async_copy16(const void* g, void* lds) {
  __builtin_amdgcn_global_load_lds((const __attribute__((address_space(1))) void*)g,
                                   (__attribute__((address_space(3))) void*)lds, 16, 0, 0);
}

__device__ __forceinline__ unsigned short f2bf(float f) {
  unsigned int u = __float_as_uint(f);
  unsigned int r = (u + 0x7fffu + ((u >> 16) & 1u)) >> 16;
  return (unsigned short)r;
}
__device__ __forceinline__ float bf2f(unsigned short h) {
  return __uint_as_float(((unsigned int)h) << 16);
}

// ---------------- K1: RMSNorm -> r[t], xn_bf16 ----------------
__global__ __launch_bounds__(256) void k1_rmsnorm(const float* __restrict__ x,
                                                  const float* __restrict__ nw,
                                                  float* __restrict__ r_out,
                                                  unsigned short* __restrict__ xn_bf) {
  int t = blockIdx.x, tid = threadIdx.x;
  const float4* xr = (const float4*)(x + (size_t)t * D_DIM);
  float4 a = xr[tid], b = xr[tid + 256];
  double ss = (double)a.x*a.x + (double)a.y*a.y + (double)a.z*a.z + (double)a.w*a.w
            + (double)b.x*b.x + (double)b.y*b.y + (double)b.z*b.z + (double)b.w*b.w;
  for (int off = 32; off; off >>= 1) ss += __shfl_down(ss, off);
  __shared__ double sred[4];
  __shared__ float rshare;
  int lane = tid & 63, wv = tid >> 6;
  if (lane == 0) sred[wv] = ss;
  __syncthreads();
  if (tid == 0) {
    double tot = sred[0] + sred[1] + sred[2] + sred[3];
    float r = (float)(1.0 / sqrt(tot / (double)D_DIM + 1.1920928955078125e-7));
    rshare = r; r_out[t] = r;
  }
  __syncthreads();
  float r = rshare;
  const float4* nw4 = (const float4*)nw;
  float4 na = nw4[tid], nb = nw4[tid + 256];
  ushort4 oa, ob;
  oa.x = f2bf(a.x * r * na.x); oa.y = f2bf(a.y * r * na.y);
  oa.z = f2bf(a.z * r * na.z); oa.w = f2bf(a.w * r * na.w);
  ob.x = f2bf(b.x * r * nb.x); ob.y = f2bf(b.y * r * nb.y);
  ob.z = f2bf(b.z * r * nb.z); ob.w = f2bf(b.w * r * nb.w);
  ushort4* o4 = (ushort4*)(xn_bf + (size_t)t * D_DIM);
  o4[tid] = oa; o4[tid + 256] = ob;
}

// ---------------- K2: Wc fp32 -> bf16 ----------------
__global__ __launch_bounds__(256) void k2_cvt(const float* __restrict__ w,
                                              unsigned short* __restrict__ wb) {
  size_t i = (size_t)blockIdx.x * 256 + threadIdx.x;   // handles 8 elements
  const float4* w4 = (const float4*)w;
  float4 a = w4[2*i], b = w4[2*i+1];
  ushort4 oa, ob;
  oa.x = f2bf(a.x); oa.y = f2bf(a.y); oa.z = f2bf(a.z); oa.w = f2bf(a.w);
  ob.x = f2bf(b.x); ob.y = f2bf(b.y); ob.z = f2bf(b.z); ob.w = f2bf(b.w);
  ((ushort4*)wb)[2*i] = oa; ((ushort4*)wb)[2*i+1] = ob;
}

// ---------------- K2b: split Wd/Wu into bf16 hi+lo ----------------
__global__ __launch_bounds__(256) void k2b_split(const float* __restrict__ wd,
                                                 const float* __restrict__ wu,
                                                 unsigned short* __restrict__ wdh,
                                                 unsigned short* __restrict__ wdl,
                                                 unsigned short* __restrict__ wuh,
                                                 unsigned short* __restrict__ wul) {
  const float* src = blockIdx.y ? wu : wd;
  unsigned short* dh = blockIdx.y ? wuh : wdh;
  unsigned short* dl = blockIdx.y ? wul : wdl;
  size_t i = (size_t)blockIdx.x * 256 + threadIdx.x;   // float4 index
  float4 v = ((const float4*)src)[i];
  ushort4 h, l;
  h.x = f2bf(v.x); l.x = f2bf(v.x - bf2f(h.x));
  h.y = f2bf(v.y); l.y = f2bf(v.y - bf2f(h.y));
  h.z = f2bf(v.z); l.z = f2bf(v.z - bf2f(h.z));
  h.w = f2bf(v.w); l.w = f2bf(v.w - bf2f(h.w));
  ((ushort4*)dh)[i] = h;
  ((ushort4*)dl)[i] = l;
}

// ---------------- K3: approx logits GEMM (bf16 MFMA, 128x128 tile) ----------------
__global__ __launch_bounds__(256) void k3_gemm_logits(const unsigned short* __restrict__ A,
                                                      const unsigned short* __restrict__ B,
                                                      unsigned short* __restrict__ C) {
  __shared__ unsigned short As[128 * 32];
  __shared__ unsigned short Bs[128 * 32];
  int tid = threadIdx.x;
  int lane = tid & 63, wv = tid >> 6;
  // bijective XCD swizzle over 2048 blocks (2048 % 8 == 0)
  int lin = blockIdx.y * gridDim.x + blockIdx.x;
  int swz = (lin & 7) * (2048 / 8) + (lin >> 3);
  int bn = swz & 31, bm = swz >> 5;
  int wr = wv >> 1, wc = wv & 1;
  f32x4 acc[4][4];
#pragma unroll
  for (int m = 0; m < 4; ++m)
#pragma unroll
    for (int n = 0; n < 4; ++n) acc[m][n] = (f32x4){0.f, 0.f, 0.f, 0.f};

  const int lrow = lane >> 2;
  const int lcol = (lane & 3) * 8;
  size_t abase = (size_t)(bm * 128) * D_DIM;
  size_t bbase = (size_t)(bn * 128) * D_DIM;

  for (int kt = 0; kt < D_DIM; kt += 32) {
    __syncthreads();
#pragma unroll
    for (int c = 0; c < 2; ++c) {
      int rr = (wv * 2 + c) * 16 + lrow;
      async_copy16(A + abase + (size_t)rr * D_DIM + kt + lcol, &As[(wv * 2 + c) * 512]);
      async_copy16(B + bbase + (size_t)rr * D_DIM + kt + lcol, &Bs[(wv * 2 + c) * 512]);
    }
    __syncthreads();
    bf16x8 fa[4], fb[4];
#pragma unroll
    for (int m = 0; m < 4; ++m)
      fa[m] = *(const bf16x8*)&As[(wr * 64 + m * 16 + (lane & 15)) * 32 + (lane >> 4) * 8];
#pragma unroll
    for (int n = 0; n < 4; ++n)
      fb[n] = *(const bf16x8*)&Bs[(wc * 64 + n * 16 + (lane & 15)) * 32 + (lane >> 4) * 8];
#pragma unroll
    for (int m = 0; m < 4; ++m)
#pragma unroll
      for (int n = 0; n < 4; ++n)
        acc[m][n] = __builtin_amdgcn_mfma_f32_16x16x32_bf16(fa[m], fb[n], acc[m][n], 0, 0, 0);
  }
#pragma unroll
  for (int m = 0; m < 4; ++m)
#pragma unroll
    for (int n = 0; n < 4; ++n)
#pragma unroll
      for (int j = 0; j < 4; ++j) {
        int row = bm * 128 + wr * 64 + m * 16 + (lane >> 4) * 4 + j;
        int col = bn * 128 + wc * 64 + n * 16 + (lane & 15);
        C[(size_t)row * G_GENES + col] = f2bf(acc[m][n][j]);
      }
}

// ---------------- K4: per-token top-40 candidates (1 wave / token) ----------------
__global__ __launch_bounds__(256) void k4_topk(const unsigned short* __restrict__ L,
                                               int* __restrict__ cand) {
  int wv = threadIdx.x >> 6, lane = threadIdx.x & 63;
  int t = blockIdx.x * 4 + wv;
  const unsigned short* lp = L + (size_t)t * G_GENES;
  float v[64];
#pragma unroll
  for (int i = 0; i < 8; ++i) {
    uint4 raw = *(const uint4*)(lp + i * 512 + lane * 8);
    v[i*8+0] = __uint_as_float(raw.x << 16);
    v[i*8+1] = __uint_as_float(raw.x & 0xffff0000u);
    v[i*8+2] = __uint_as_float(raw.y << 16);
    v[i*8+3] = __uint_as_float(raw.y & 0xffff0000u);
    v[i*8+4] = __uint_as_float(raw.z << 16);
    v[i*8+5] = __uint_as_float(raw.z & 0xffff0000u);
    v[i*8+6] = __uint_as_float(raw.w << 16);
    v[i*8+7] = __uint_as_float(raw.w & 0xffff0000u);
  }
  unsigned long long alive = ~0ull;
  for (int it = 0; it < NCAND; ++it) {
    float best = -3.0e38f; int bslot = 0;
#pragma unroll
    for (int s = 0; s < 64; ++s) {
      bool ok = (alive >> s) & 1ull;
      if (ok && v[s] > best) { best = v[s]; bslot = s; }
    }
    unsigned int g = ((unsigned)(bslot >> 3)) * 512u + (unsigned)lane * 8u + (unsigned)(bslot & 7);
    float m = best; unsigned int mg = g;
#pragma unroll
    for (int off = 32; off; off >>= 1) {
      float om = __shfl_xor(m, off);
      unsigned int og = __shfl_xor(mg, off);
      if (om > m || (om == m && og < mg)) { m = om; mg = og; }
    }
    if (lane == (int)((mg >> 3) & 63u)) {
      int s = (int)(((mg >> 9) << 3) | (mg & 7u));
      alive &= ~(1ull << s);
    }
    if (lane == 0) cand[(size_t)t * NCAND + it] = (int)mg;
  }
}

// ---------------- K5a: fp64 partial rescore, D-sliced for L2 residency ----------------
// slice = blockIdx.x & 7 rides round-robin block->XCD dispatch. Slice s owns
// D-chunk [s*256,(s+1)*256): its Wc column-slice is 4096x256x4B = 4MB = one
// XCD's L2, and x is read exactly once (1KB chunk per token per slice).
// Each (t,cand) pair -> fp64 partial dot over 256 elems; k6 sums 8 partials.
// 8 candidates batched per inner iter: 8-way interleaved loads/FMAs/shuffles.
__global__ __launch_bounds__(256) void k5a_partial(const float* __restrict__ x,
                                                   const float* __restrict__ r,
                                                   const float* __restrict__ nw,
                                                   const float* __restrict__ Wc,
                                                   const int* __restrict__ cand,
                                                   double* __restrict__ part) {
  int bid = blockIdx.x;
  int slice = bid & 7;
  int group = bid >> 3;
  int wv = threadIdx.x >> 6, lane = threadIdx.x & 63;
  const int dbase = slice * 256;
  float4 nv = *(const float4*)(nw + dbase + lane * 4);
#pragma unroll 1
  for (int tt = 0; tt < 2; ++tt) {
    int t = group * 8 + wv * 2 + tt;
    float rr = r[t];
    float4 xv = *(const float4*)(x + (size_t)t * D_DIM + dbase + lane * 4);
    float4 xl;
    xl.x = xv.x * rr * nv.x;
    xl.y = xv.y * rr * nv.y;
    xl.z = xv.z * rr * nv.z;
    xl.w = xv.w * rr * nv.w;
    int myg = cand[t * NCAND + (lane < NCAND ? lane : 0)];
    double* outp = part + ((size_t)t * NSLICE + slice) * NCAND;
#pragma unroll 1
    for (int j0 = 0; j0 < NCAND; j0 += 8) {
      float4 w[8];
#pragma unroll
      for (int c = 0; c < 8; ++c) {
        int g = __shfl(myg, j0 + c);
        w[c] = *(const float4*)(Wc + (size_t)g * D_DIM + dbase + lane * 4);
      }
      double s[8];
#pragma unroll
      for (int c = 0; c < 8; ++c)
        s[c] = ((double)xl.x * (double)w[c].x + (double)xl.y * (double)w[c].y)
             + ((double)xl.z * (double)w[c].z + (double)xl.w * (double)w[c].w);
#pragma unroll
      for (int off = 32; off; off >>= 1) {
#pragma unroll
        for (int c = 0; c < 8; ++c) s[c] += __shfl_down(s[c], off);
      }
      if (lane == 0) {
#pragma unroll
        for (int c = 0; c < 8; ++c) outp[j0 + c] = s[c];
      }
    }
  }
}

// ---------------- K6: sum partials, select top-32, softmax, combine ----------------
__global__ __launch_bounds__(256) void k6_express(const double* __restrict__ part,
                                                  const int* __restrict__ cand,
                                                  const float* __restrict__ genes,
                                                  const float* __restrict__ temp,
                                                  unsigned short* __restrict__ e_hi,
                                                  unsigned short* __restrict__ e_lo) {
  int t = blockIdx.x, tid = threadIdx.x;
  __shared__ double sval[NCAND];
  __shared__ int sidx[NCAND];
  __shared__ float sw[NCAND];
  float tclamp = fmaxf(temp[0], 0.1f);
  if (tid < NCAND) {
    const double* pp = part + (size_t)t * NSLICE * NCAND + tid;
    double v = 0.0;
#pragma unroll
    for (int s = 0; s < NSLICE; ++s) v += pp[s * NCAND];
    sval[tid] = v / (double)tclamp;
    sidx[tid] = cand[(size_t)t * NCAND + tid];
  }
  __syncthreads();
  if (tid < 64) {
    double v = (tid < NCAND) ? sval[tid] : -1.0e300;
    int gi = (tid < NCAND) ? sidx[tid] : 0x7fffffff;
    int rank = 0;
    for (int j = 0; j < NCAND; ++j) {
      double vj = sval[j]; int gj = sidx[j];
      if (vj > v || (vj == v && gj < gi)) rank++;
    }
    bool sel = (tid < NCAND) && (rank < KSEL);
    double vs = sel ? v : -1.0e300;
    double mx = vs;
    for (int off = 32; off; off >>= 1) { double o = __shfl_xor(mx, off); mx = fmax(mx, o); }
    double e = sel ? exp(v - mx) : 0.0;
    double ssum = e;
    for (int off = 32; off; off >>= 1) ssum += __shfl_xor(ssum, off);
    if (tid < NCAND) sw[tid] = (float)(e / ssum);
  }
  __syncthreads();
  float a0 = 0.f, a1 = 0.f, a2 = 0.f, a3 = 0.f;
#pragma unroll
  for (int k = 0; k < NCAND; k += 4) {
    a0 += sw[k]     * genes[(size_t)sidx[k]     * GD_DIM + tid];
    a1 += sw[k + 1] * genes[(size_t)sidx[k + 1] * GD_DIM + tid];
    a2 += sw[k + 2] * genes[(size_t)sidx[k + 2] * GD_DIM + tid];
    a3 += sw[k + 3] * genes[(size_t)sidx[k + 3] * GD_DIM + tid];
  }
  float acc = (a0 + a1) + (a2 + a3);
  unsigned short h = f2bf(acc);
  unsigned short l = f2bf(acc - bf2f(h));
  e_hi[(size_t)t * GD_DIM + tid] = h;
  e_lo[(size_t)t * GD_DIM + tid] = l;
}

// ---------------- K7: bf16-split MFMA down/up GEMM + tanh + xn + scale -> out ----------------
__global__ __launch_bounds__(256) void k7_mfma(const unsigned short* __restrict__ e_hi,
                                               const unsigned short* __restrict__ e_lo,
                                               const unsigned short* __restrict__ wdh,
                                               const unsigned short* __restrict__ wdl,
                                               const unsigned short* __restrict__ wuh,
                                               const unsigned short* __restrict__ wul,
                                               const float* __restrict__ x,
                                               const float* __restrict__ r,
                                               const float* __restrict__ nw,
                                               const float* __restrict__ scale_p,
                                               float* __restrict__ out) {
  __shared__ unsigned short Ah[128 * 32], Al[128 * 32];
  __shared__ unsigned short Dh[64 * 32], Dl[64 * 32], Uh[64 * 32], Ul[64 * 32];
  int tid = threadIdx.x;
  int lane = tid & 63, wv = tid >> 6;
  int bn = blockIdx.x, bm = blockIdx.y;
  int wr = wv >> 1, wc = wv & 1;   // wave tile: 64(M) x 32(N)
  const int lrow = lane >> 2;
  const int lcol = (lane & 3) * 8;

  f32x4 accD[4][2], accU[4][2];
#pragma unroll
  for (int m = 0; m < 4; ++m)
#pragma unroll
    for (int n = 0; n < 2; ++n) {
      accD[m][n] = (f32x4){0.f, 0.f, 0.f, 0.f};
      accU[m][n] = (f32x4){0.f, 0.f, 0.f, 0.f};
    }

  for (int kt = 0; kt < GD_DIM; kt += 32) {
    __syncthreads();
#pragma unroll
    for (int c = 0; c < 8; ++c) {
      int cid = wv * 8 + c;
      if (cid < 8) {
        async_copy16(e_hi + (size_t)(bm * 128 + cid * 16 + lrow) * GD_DIM + kt + lcol,
                     &Ah[cid * 512]);
      } else if (cid < 16) {
        int cc = cid - 8;
        async_copy16(e_lo + (size_t)(bm * 128 + cc * 16 + lrow) * GD_DIM + kt + lcol,
                     &Al[cc * 512]);
      } else if (cid < 20) {
        int cc = cid - 16;
        async_copy16(wdh + (size_t)(bn * 64 + cc * 16 + lrow) * GD_DIM + kt + lcol,
                     &Dh[cc * 512]);
      } else if (cid < 24) {
        int cc = cid - 20;
        async_copy16(wdl + (size_t)(bn * 64 + cc * 16 + lrow) * GD_DIM + kt + lcol,
                     &Dl[cc * 512]);
      } else if (cid < 28) {
        int cc = cid - 24;
        async_copy16(wuh + (size_t)(bn * 64 + cc * 16 + lrow) * GD_DIM + kt + lcol,
                     &Uh[cc * 512]);
      } else {
        int cc = cid - 28;
        async_copy16(wul + (size_t)(bn * 64 + cc * 16 + lrow) * GD_DIM + kt + lcol,
                     &Ul[cc * 512]);
      }
    }
    __syncthreads();
    bf16x8 fah[4], fal[4], fdh[2], fdl[2], fuh[2], ful[2];
#pragma unroll
    for (int m = 0; m < 4; ++m) {
      int off = (wr * 64 + m * 16 + (lane & 15)) * 32 + (lane >> 4) * 8;
      fah[m] = *(const bf16x8*)&Ah[off];
      fal[m] = *(const bf16x8*)&Al[off];
    }
#pragma unroll
    for (int n = 0; n < 2; ++n) {
      int off = (wc * 32 + n * 16 + (lane & 15)) * 32 + (lane >> 4) * 8;
      fdh[n] = *(const bf16x8*)&Dh[off];
      fdl[n] = *(const bf16x8*)&Dl[off];
      fuh[n] = *(const bf16x8*)&Uh[off];
      ful[n] = *(const bf16x8*)&Ul[off];
    }
#pragma unroll
    for (int m = 0; m < 4; ++m)
#pragma unroll
      for (int n = 0; n < 2; ++n) {
        accD[m][n] = __builtin_amdgcn_mfma_f32_16x16x32_bf16(fah[m], fdh[n], accD[m][n], 0, 0, 0);
        accD[m][n] = __builtin_amdgcn_mfma_f32_16x16x32_bf16(fah[m], fdl[n], accD[m][n], 0, 0, 0);
        accD[m][n] = __builtin_amdgcn_mfma_f32_16x16x32_bf16(fal[m], fdh[n], accD[m][n], 0, 0, 0);
        accU[m][n] = __builtin_amdgcn_mfma_f32_16x16x32_bf16(fah[m], fuh[n], accU[m][n], 0, 0, 0);
        accU[m][n] = __builtin_amdgcn_mfma_f32_16x16x32_bf16(fah[m], ful[n], accU[m][n], 0, 0, 0);
        accU[m][n] = __builtin_amdgcn_mfma_f32_16x16x32_bf16(fal[m], fuh[n], accU[m][n], 0, 0, 0);
      }
  }
  float sc = scale_p[0];
#pragma unroll
  for (int m = 0; m < 4; ++m)
#pragma unroll
    for (int j = 0; j < 4; ++j) {
      int token = bm * 128 + wr * 64 + m * 16 + (lane >> 4) * 4 + j;
      float rr = r[token];
#pragma unroll
      for (int n = 0; n < 2; ++n) {
        int d = bn * 64 + wc * 32 + n * 16 + (lane & 15);
        float xn = x[(size_t)token * D_DIM + d] * rr * nw[d];
        out[(size_t)token * D_DIM + d] = tanhf(accD[m][n][j]) * xn * accU[m][n][j] * sc;
      }
    }
}

extern "C" void kernel_launch(void* const* d_in, const int* in_sizes, int n_in,
                              void* d_out, int out_size, void* d_ws, size_t ws_size,
                              hipStream_t stream) {
  const float* x       = (const float*)d_in[0];
  const float* Wc      = (const float*)d_in[1];
  const float* temp    = (const float*)d_in[2];
  const float* genes   = (const float*)d_in[3];
  const float* Wd      = (const float*)d_in[4];
  const float* Wu      = (const float*)d_in[5];
  const float* nw      = (const float*)d_in[6];
  const float* scale_p = (const float*)d_in[7];

  char* ws = (char*)d_ws;
  float* r_buf          = (float*)ws;                                   // 32 KB (64 KB reserved)
  unsigned short* xn_bf = (unsigned short*)(ws + 65536);                // 32 MB (free after k3)
  unsigned short* wc_bf = (unsigned short*)(ws + 65536 + (size_t)M_TOK * D_DIM * 2);   // 16 MB
  char* p = ws + 65536 + (size_t)M_TOK * D_DIM * 2 + (size_t)G_GENES * D_DIM * 2;
  int* cand    = (int*)p;                       p += (size_t)M_TOK * NCAND * 4;
  p += (size_t)M_TOK * NCAND * 8;               // (former cval slot, unused)
  unsigned short* e_hi = (unsigned short*)p;    p += (size_t)M_TOK * GD_DIM * 2;
  unsigned short* e_lo = (unsigned short*)p;

  // Wd/Wu bf16 hi/lo splits live in the xn_bf region (dead after k3): 4 x 1 MB
  unsigned short* wdh = (unsigned short*)(ws + 65536);
  unsigned short* wdl = wdh + (size_t)D_DIM * GD_DIM;
  unsigned short* wuh = wdl + (size_t)D_DIM * GD_DIM;
  unsigned short* wul = wuh + (size_t)D_DIM * GD_DIM;
  // fp64 partials also in the dead xn_bf region, after the 4 MB of splits:
  // 8192 x 8 x 40 x 8B = 21 MB (region holds 32 MB total)
  double* part = (double*)(ws + 65536 + 4ull * D_DIM * GD_DIM * 2);

  unsigned short* logits_bf = (unsigned short*)d_out;  // 33.5M bf16 == 64 MB == d_out

  k1_rmsnorm<<<dim3(M_TOK), dim3(256), 0, stream>>>(x, nw, r_buf, xn_bf);
  k2_cvt<<<dim3((G_GENES * D_DIM) / (256 * 8)), dim3(256), 0, stream>>>(Wc, wc_bf);
  k3_gemm_logits<<<dim3(G_GENES / 128, M_TOK / 128), dim3(256), 0, stream>>>(xn_bf, wc_bf, logits_bf);
  k4_topk<<<dim3(M_TOK / 4), dim3(256), 0, stream>>>(logits_bf, cand);
  k2b_split<<<dim3((D_DIM * GD_DIM) / (256 * 4), 2), dim3(256), 0, stream>>>(Wd, Wu, wdh, wdl, wuh, wul);
  k5a_partial<<<dim3(M_TOK), dim3(256), 0, stream>>>(x, r_buf, nw, Wc, cand, part);
  k6_express<<<dim3(M_TOK), dim3(256), 0, stream>>>(part, cand, genes, temp, e_hi, e_lo);
  k7_mfma<<<dim3(D_DIM / 64, M_TOK / 128), dim3(256), 0, stream>>>(e_hi, e_lo, wdh, wdl, wuh, wul,
                                                                   x, r_buf, nw, scale_p, (float*)d_out);
}

// Round 6
// 695.214 us; speedup vs baseline: 1.3337x; 1.3213x over previous
//
#include <hip/hip_runtime.h>
#include <math.h>

#define M_TOK 8192
#define D_DIM 2048
#define G_GENES 4096
#define GD_DIM 256
#define KSEL 32
#define NCAND 40
#define NSLICE 8

typedef float f32x4 __attribute__((ext_vector_type(4)));
typedef short bf16x8 __attribute__((ext_vector_type(8)));

__device__ __forceinline__ void async_copy16(const void* g, void* lds) {
  __builtin_amdgcn_global_load_lds((const __attribute__((address_space(1))) void*)g,
                                   (__attribute__((address_space(3))) void*)lds, 16, 0, 0);
}

__device__ __forceinline__ unsigned short f2bf(float f) {
  unsigned int u = __float_as_uint(f);
  unsigned int r = (u + 0x7fffu + ((u >> 16) & 1u)) >> 16;
  return (unsigned short)r;
}
__device__ __forceinline__ float bf2f(unsigned short h) {
  return __uint_as_float(((unsigned int)h) << 16);
}

// ---------------- K1: RMSNorm -> r[t], xn_bf16 ----------------
__global__ __launch_bounds__(256) void k1_rmsnorm(const float* __restrict__ x,
                                                  const float* __restrict__ nw,
                                                  float* __restrict__ r_out,
                                                  unsigned short* __restrict__ xn_bf) {
  int t = blockIdx.x, tid = threadIdx.x;
  const float4* xr = (const float4*)(x + (size_t)t * D_DIM);
  float4 a = xr[tid], b = xr[tid + 256];
  double ss = (double)a.x*a.x + (double)a.y*a.y + (double)a.z*a.z + (double)a.w*a.w
            + (double)b.x*b.x + (double)b.y*b.y + (double)b.z*b.z + (double)b.w*b.w;
  for (int off = 32; off; off >>= 1) ss += __shfl_down(ss, off);
  __shared__ double sred[4];
  __shared__ float rshare;
  int lane = tid & 63, wv = tid >> 6;
  if (lane == 0) sred[wv] = ss;
  __syncthreads();
  if (tid == 0) {
    double tot = sred[0] + sred[1] + sred[2] + sred[3];
    float r = (float)(1.0 / sqrt(tot / (double)D_DIM + 1.1920928955078125e-7));
    rshare = r; r_out[t] = r;
  }
  __syncthreads();
  float r = rshare;
  const float4* nw4 = (const float4*)nw;
  float4 na = nw4[tid], nb = nw4[tid + 256];
  ushort4 oa, ob;
  oa.x = f2bf(a.x * r * na.x); oa.y = f2bf(a.y * r * na.y);
  oa.z = f2bf(a.z * r * na.z); oa.w = f2bf(a.w * r * na.w);
  ob.x = f2bf(b.x * r * nb.x); ob.y = f2bf(b.y * r * nb.y);
  ob.z = f2bf(b.z * r * nb.z); ob.w = f2bf(b.w * r * nb.w);
  ushort4* o4 = (ushort4*)(xn_bf + (size_t)t * D_DIM);
  o4[tid] = oa; o4[tid + 256] = ob;
}

// ---------------- K2: Wc fp32 -> bf16 ----------------
__global__ __launch_bounds__(256) void k2_cvt(const float* __restrict__ w,
                                              unsigned short* __restrict__ wb) {
  size_t i = (size_t)blockIdx.x * 256 + threadIdx.x;   // handles 8 elements
  const float4* w4 = (const float4*)w;
  float4 a = w4[2*i], b = w4[2*i+1];
  ushort4 oa, ob;
  oa.x = f2bf(a.x); oa.y = f2bf(a.y); oa.z = f2bf(a.z); oa.w = f2bf(a.w);
  ob.x = f2bf(b.x); ob.y = f2bf(b.y); ob.z = f2bf(b.z); ob.w = f2bf(b.w);
  ((ushort4*)wb)[2*i] = oa; ((ushort4*)wb)[2*i+1] = ob;
}

// ---------------- K2b: split Wd/Wu into bf16 hi+lo ----------------
__global__ __launch_bounds__(256) void k2b_split(const float* __restrict__ wd,
                                                 const float* __restrict__ wu,
                                                 unsigned short* __restrict__ wdh,
                                                 unsigned short* __restrict__ wdl,
                                                 unsigned short* __restrict__ wuh,
                                                 unsigned short* __restrict__ wul) {
  const float* src = blockIdx.y ? wu : wd;
  unsigned short* dh = blockIdx.y ? wuh : wdh;
  unsigned short* dl = blockIdx.y ? wul : wdl;
  size_t i = (size_t)blockIdx.x * 256 + threadIdx.x;   // float4 index
  float4 v = ((const float4*)src)[i];
  ushort4 h, l;
  h.x = f2bf(v.x); l.x = f2bf(v.x - bf2f(h.x));
  h.y = f2bf(v.y); l.y = f2bf(v.y - bf2f(h.y));
  h.z = f2bf(v.z); l.z = f2bf(v.z - bf2f(h.z));
  h.w = f2bf(v.w); l.w = f2bf(v.w - bf2f(h.w));
  ((ushort4*)dh)[i] = h;
  ((ushort4*)dl)[i] = l;
}

// ---------------- K3: approx logits GEMM (bf16 MFMA, 128x128 tile) ----------------
__global__ __launch_bounds__(256) void k3_gemm_logits(const unsigned short* __restrict__ A,
                                                      const unsigned short* __restrict__ B,
                                                      unsigned short* __restrict__ C) {
  __shared__ unsigned short As[128 * 32];
  __shared__ unsigned short Bs[128 * 32];
  int tid = threadIdx.x;
  int lane = tid & 63, wv = tid >> 6;
  // bijective XCD swizzle over 2048 blocks (2048 % 8 == 0)
  int lin = blockIdx.y * gridDim.x + blockIdx.x;
  int swz = (lin & 7) * (2048 / 8) + (lin >> 3);
  int bn = swz & 31, bm = swz >> 5;
  int wr = wv >> 1, wc = wv & 1;
  f32x4 acc[4][4];
#pragma unroll
  for (int m = 0; m < 4; ++m)
#pragma unroll
    for (int n = 0; n < 4; ++n) acc[m][n] = (f32x4){0.f, 0.f, 0.f, 0.f};

  const int lrow = lane >> 2;
  const int lcol = (lane & 3) * 8;
  size_t abase = (size_t)(bm * 128) * D_DIM;
  size_t bbase = (size_t)(bn * 128) * D_DIM;

  for (int kt = 0; kt < D_DIM; kt += 32) {
    __syncthreads();
#pragma unroll
    for (int c = 0; c < 2; ++c) {
      int rr = (wv * 2 + c) * 16 + lrow;
      async_copy16(A + abase + (size_t)rr * D_DIM + kt + lcol, &As[(wv * 2 + c) * 512]);
      async_copy16(B + bbase + (size_t)rr * D_DIM + kt + lcol, &Bs[(wv * 2 + c) * 512]);
    }
    __syncthreads();
    bf16x8 fa[4], fb[4];
#pragma unroll
    for (int m = 0; m < 4; ++m)
      fa[m] = *(const bf16x8*)&As[(wr * 64 + m * 16 + (lane & 15)) * 32 + (lane >> 4) * 8];
#pragma unroll
    for (int n = 0; n < 4; ++n)
      fb[n] = *(const bf16x8*)&Bs[(wc * 64 + n * 16 + (lane & 15)) * 32 + (lane >> 4) * 8];
#pragma unroll
    for (int m = 0; m < 4; ++m)
#pragma unroll
      for (int n = 0; n < 4; ++n)
        acc[m][n] = __builtin_amdgcn_mfma_f32_16x16x32_bf16(fa[m], fb[n], acc[m][n], 0, 0, 0);
  }
#pragma unroll
  for (int m = 0; m < 4; ++m)
#pragma unroll
    for (int n = 0; n < 4; ++n)
#pragma unroll
      for (int j = 0; j < 4; ++j) {
        int row = bm * 128 + wr * 64 + m * 16 + (lane >> 4) * 4 + j;
        int col = bn * 128 + wc * 64 + n * 16 + (lane & 15);
        C[(size_t)row * G_GENES + col] = f2bf(acc[m][n][j]);
      }
}

// ---------------- K4: per-token top-40 candidates (1 wave / token) ----------------
__global__ __launch_bounds__(256) void k4_topk(const unsigned short* __restrict__ L,
                                               int* __restrict__ cand) {
  int wv = threadIdx.x >> 6, lane = threadIdx.x & 63;
  int t = blockIdx.x * 4 + wv;
  const unsigned short* lp = L + (size_t)t * G_GENES;
  float v[64];
#pragma unroll
  for (int i = 0; i < 8; ++i) {
    uint4 raw = *(const uint4*)(lp + i * 512 + lane * 8);
    v[i*8+0] = __uint_as_float(raw.x << 16);
    v[i*8+1] = __uint_as_float(raw.x & 0xffff0000u);
    v[i*8+2] = __uint_as_float(raw.y << 16);
    v[i*8+3] = __uint_as_float(raw.y & 0xffff0000u);
    v[i*8+4] = __uint_as_float(raw.z << 16);
    v[i*8+5] = __uint_as_float(raw.z & 0xffff0000u);
    v[i*8+6] = __uint_as_float(raw.w << 16);
    v[i*8+7] = __uint_as_float(raw.w & 0xffff0000u);
  }
  unsigned long long alive = ~0ull;
  for (int it = 0; it < NCAND; ++it) {
    float best = -3.0e38f; int bslot = 0;
#pragma unroll
    for (int s = 0; s < 64; ++s) {
      bool ok = (alive >> s) & 1ull;
      if (ok && v[s] > best) { best = v[s]; bslot = s; }
    }
    unsigned int g = ((unsigned)(bslot >> 3)) * 512u + (unsigned)lane * 8u + (unsigned)(bslot & 7);
    float m = best; unsigned int mg = g;
#pragma unroll
    for (int off = 32; off; off >>= 1) {
      float om = __shfl_xor(m, off);
      unsigned int og = __shfl_xor(mg, off);
      if (om > m || (om == m && og < mg)) { m = om; mg = og; }
    }
    if (lane == (int)((mg >> 3) & 63u)) {
      int s = (int)(((mg >> 9) << 3) | (mg & 7u));
      alive &= ~(1ull << s);
    }
    if (lane == 0) cand[(size_t)t * NCAND + it] = (int)mg;
  }
}

// ---------------- K5a: fp64 partial rescore, D-sliced, compress-tree reduce ----------------
// D-slicing as R5 (x read once, Wc slice L2-resident per XCD). Reduction uses a
// compress tree: stages over lane bits 0..2 halve the register count each time
// (keep one candidate, forward the other), then 3 single-register stages over
// bits 3..5. 10 fp64 shuffles per 8-candidate batch instead of 48. After the
// tree, lane l holds the full total for candidate l&7; lanes 0-7 store.
__global__ __launch_bounds__(256) void k5a_partial(const float* __restrict__ x,
                                                   const float* __restrict__ r,
                                                   const float* __restrict__ nw,
                                                   const float* __restrict__ Wc,
                                                   const int* __restrict__ cand,
                                                   double* __restrict__ part) {
  int bid = blockIdx.x;
  int slice = bid & 7;
  int group = bid >> 3;
  int wv = threadIdx.x >> 6, lane = threadIdx.x & 63;
  const int dbase = slice * 256;
  float4 nv = *(const float4*)(nw + dbase + lane * 4);
  bool b0 = (lane & 1) != 0, b1 = (lane & 2) != 0, b2 = (lane & 4) != 0;
#pragma unroll 1
  for (int tt = 0; tt < 2; ++tt) {
    int t = group * 8 + wv * 2 + tt;
    float rr = r[t];
    float4 xv = *(const float4*)(x + (size_t)t * D_DIM + dbase + lane * 4);
    float4 xl;
    xl.x = xv.x * rr * nv.x;
    xl.y = xv.y * rr * nv.y;
    xl.z = xv.z * rr * nv.z;
    xl.w = xv.w * rr * nv.w;
    int myg = cand[t * NCAND + (lane < NCAND ? lane : 0)];
    double* outp = part + ((size_t)t * NSLICE + slice) * NCAND;
#pragma unroll 1
    for (int j0 = 0; j0 < NCAND; j0 += 8) {
      float4 w[8];
#pragma unroll
      for (int c = 0; c < 8; ++c) {
        int g = __shfl(myg, j0 + c);
        w[c] = *(const float4*)(Wc + (size_t)g * D_DIM + dbase + lane * 4);
      }
      double s[8];
#pragma unroll
      for (int c = 0; c < 8; ++c)
        s[c] = ((double)xl.x * (double)w[c].x + (double)xl.y * (double)w[c].y)
             + ((double)xl.z * (double)w[c].z + (double)xl.w * (double)w[c].w);
      // stage A (bit0): 8 -> 4 regs
      double u01 = b0 ? s[1] : s[0], t01 = b0 ? s[0] : s[1];
      double u23 = b0 ? s[3] : s[2], t23 = b0 ? s[2] : s[3];
      double u45 = b0 ? s[5] : s[4], t45 = b0 ? s[4] : s[5];
      double u67 = b0 ? s[7] : s[6], t67 = b0 ? s[6] : s[7];
      u01 += __shfl_xor(t01, 1);
      u23 += __shfl_xor(t23, 1);
      u45 += __shfl_xor(t45, 1);
      u67 += __shfl_xor(t67, 1);
      // stage B (bit1): 4 -> 2 regs
      double v03 = b1 ? u23 : u01, t03 = b1 ? u01 : u23;
      double v47 = b1 ? u67 : u45, t47 = b1 ? u45 : u67;
      v03 += __shfl_xor(t03, 2);
      v47 += __shfl_xor(t47, 2);
      // stage C (bit2): 2 -> 1 reg; now lane l holds candidate (l&7) group-sum
      double wsum = b2 ? v47 : v03, t07 = b2 ? v03 : v47;
      wsum += __shfl_xor(t07, 4);
      // stages D-F: reduce across 8-lane groups
      wsum += __shfl_xor(wsum, 8);
      wsum += __shfl_xor(wsum, 16);
      wsum += __shfl_xor(wsum, 32);
      if (lane < 8) outp[j0 + lane] = wsum;
    }
  }
}

// ---------------- K6: sum partials, select top-32, softmax, combine ----------------
__global__ __launch_bounds__(256) void k6_express(const double* __restrict__ part,
                                                  const int* __restrict__ cand,
                                                  const float* __restrict__ genes,
                                                  const float* __restrict__ temp,
                                                  unsigned short* __restrict__ e_hi,
                                                  unsigned short* __restrict__ e_lo) {
  int t = blockIdx.x, tid = threadIdx.x;
  __shared__ double sval[NCAND];
  __shared__ int sidx[NCAND];
  __shared__ float sw[NCAND];
  float tclamp = fmaxf(temp[0], 0.1f);
  if (tid < NCAND) {
    const double* pp = part + (size_t)t * NSLICE * NCAND + tid;
    double v = 0.0;
#pragma unroll
    for (int s = 0; s < NSLICE; ++s) v += pp[s * NCAND];
    sval[tid] = v / (double)tclamp;
    sidx[tid] = cand[(size_t)t * NCAND + tid];
  }
  __syncthreads();
  if (tid < 64) {
    double v = (tid < NCAND) ? sval[tid] : -1.0e300;
    int gi = (tid < NCAND) ? sidx[tid] : 0x7fffffff;
    int rank = 0;
    for (int j = 0; j < NCAND; ++j) {
      double vj = sval[j]; int gj = sidx[j];
      if (vj > v || (vj == v && gj < gi)) rank++;
    }
    bool sel = (tid < NCAND) && (rank < KSEL);
    double vs = sel ? v : -1.0e300;
    double mx = vs;
    for (int off = 32; off; off >>= 1) { double o = __shfl_xor(mx, off); mx = fmax(mx, o); }
    double e = sel ? exp(v - mx) : 0.0;
    double ssum = e;
    for (int off = 32; off; off >>= 1) ssum += __shfl_xor(ssum, off);
    if (tid < NCAND) sw[tid] = (float)(e / ssum);
  }
  __syncthreads();
  float a0 = 0.f, a1 = 0.f, a2 = 0.f, a3 = 0.f;
#pragma unroll
  for (int k = 0; k < NCAND; k += 4) {
    a0 += sw[k]     * genes[(size_t)sidx[k]     * GD_DIM + tid];
    a1 += sw[k + 1] * genes[(size_t)sidx[k + 1] * GD_DIM + tid];
    a2 += sw[k + 2] * genes[(size_t)sidx[k + 2] * GD_DIM + tid];
    a3 += sw[k + 3] * genes[(size_t)sidx[k + 3] * GD_DIM + tid];
  }
  float acc = (a0 + a1) + (a2 + a3);
  unsigned short h = f2bf(acc);
  unsigned short l = f2bf(acc - bf2f(h));
  e_hi[(size_t)t * GD_DIM + tid] = h;
  e_lo[(size_t)t * GD_DIM + tid] = l;
}

// ---------------- K7: bf16-split MFMA down/up GEMM + tanh + xn + scale -> out ----------------
__global__ __launch_bounds__(256) void k7_mfma(const unsigned short* __restrict__ e_hi,
                                               const unsigned short* __restrict__ e_lo,
                                               const unsigned short* __restrict__ wdh,
                                               const unsigned short* __restrict__ wdl,
                                               const unsigned short* __restrict__ wuh,
                                               const unsigned short* __restrict__ wul,
                                               const float* __restrict__ x,
                                               const float* __restrict__ r,
                                               const float* __restrict__ nw,
                                               const float* __restrict__ scale_p,
                                               float* __restrict__ out) {
  __shared__ unsigned short Ah[128 * 32], Al[128 * 32];
  __shared__ unsigned short Dh[64 * 32], Dl[64 * 32], Uh[64 * 32], Ul[64 * 32];
  int tid = threadIdx.x;
  int lane = tid & 63, wv = tid >> 6;
  int bn = blockIdx.x, bm = blockIdx.y;
  int wr = wv >> 1, wc = wv & 1;   // wave tile: 64(M) x 32(N)
  const int lrow = lane >> 2;
  const int lcol = (lane & 3) * 8;

  f32x4 accD[4][2], accU[4][2];
#pragma unroll
  for (int m = 0; m < 4; ++m)
#pragma unroll
    for (int n = 0; n < 2; ++n) {
      accD[m][n] = (f32x4){0.f, 0.f, 0.f, 0.f};
      accU[m][n] = (f32x4){0.f, 0.f, 0.f, 0.f};
    }

  for (int kt = 0; kt < GD_DIM; kt += 32) {
    __syncthreads();
#pragma unroll
    for (int c = 0; c < 8; ++c) {
      int cid = wv * 8 + c;
      if (cid < 8) {
        async_copy16(e_hi + (size_t)(bm * 128 + cid * 16 + lrow) * GD_DIM + kt + lcol,
                     &Ah[cid * 512]);
      } else if (cid < 16) {
        int cc = cid - 8;
        async_copy16(e_lo + (size_t)(bm * 128 + cc * 16 + lrow) * GD_DIM + kt + lcol,
                     &Al[cc * 512]);
      } else if (cid < 20) {
        int cc = cid - 16;
        async_copy16(wdh + (size_t)(bn * 64 + cc * 16 + lrow) * GD_DIM + kt + lcol,
                     &Dh[cc * 512]);
      } else if (cid < 24) {
        int cc = cid - 20;
        async_copy16(wdl + (size_t)(bn * 64 + cc * 16 + lrow) * GD_DIM + kt + lcol,
                     &Dl[cc * 512]);
      } else if (cid < 28) {
        int cc = cid - 24;
        async_copy16(wuh + (size_t)(bn * 64 + cc * 16 + lrow) * GD_DIM + kt + lcol,
                     &Uh[cc * 512]);
      } else {
        int cc = cid - 28;
        async_copy16(wul + (size_t)(bn * 64 + cc * 16 + lrow) * GD_DIM + kt + lcol,
                     &Ul[cc * 512]);
      }
    }
    __syncthreads();
    bf16x8 fah[4], fal[4], fdh[2], fdl[2], fuh[2], ful[2];
#pragma unroll
    for (int m = 0; m < 4; ++m) {
      int off = (wr * 64 + m * 16 + (lane & 15)) * 32 + (lane >> 4) * 8;
      fah[m] = *(const bf16x8*)&Ah[off];
      fal[m] = *(const bf16x8*)&Al[off];
    }
#pragma unroll
    for (int n = 0; n < 2; ++n) {
      int off = (wc * 32 + n * 16 + (lane & 15)) * 32 + (lane >> 4) * 8;
      fdh[n] = *(const bf16x8*)&Dh[off];
      fdl[n] = *(const bf16x8*)&Dl[off];
      fuh[n] = *(const bf16x8*)&Uh[off];
      ful[n] = *(const bf16x8*)&Ul[off];
    }
#pragma unroll
    for (int m = 0; m < 4; ++m)
#pragma unroll
      for (int n = 0; n < 2; ++n) {
        accD[m][n] = __builtin_amdgcn_mfma_f32_16x16x32_bf16(fah[m], fdh[n], accD[m][n], 0, 0, 0);
        accD[m][n] = __builtin_amdgcn_mfma_f32_16x16x32_bf16(fah[m], fdl[n], accD[m][n], 0, 0, 0);
        accD[m][n] = __builtin_amdgcn_mfma_f32_16x16x32_bf16(fal[m], fdh[n], accD[m][n], 0, 0, 0);
        accU[m][n] = __builtin_amdgcn_mfma_f32_16x16x32_bf16(fah[m], fuh[n], accU[m][n], 0, 0, 0);
        accU[m][n] = __builtin_amdgcn_mfma_f32_16x16x32_bf16(fah[m], ful[n], accU[m][n], 0, 0, 0);
        accU[m][n] = __builtin_amdgcn_mfma_f32_16x16x32_bf16(fal[m], fuh[n], accU[m][n], 0, 0, 0);
      }
  }
  float sc = scale_p[0];
#pragma unroll
  for (int m = 0; m < 4; ++m)
#pragma unroll
    for (int j = 0; j < 4; ++j) {
      int token = bm * 128 + wr * 64 + m * 16 + (lane >> 4) * 4 + j;
      float rr = r[token];
#pragma unroll
      for (int n = 0; n < 2; ++n) {
        int d = bn * 64 + wc * 32 + n * 16 + (lane & 15);
        float xn = x[(size_t)token * D_DIM + d] * rr * nw[d];
        out[(size_t)token * D_DIM + d] = tanhf(accD[m][n][j]) * xn * accU[m][n][j] * sc;
      }
    }
}

extern "C" void kernel_launch(void* const* d_in, const int* in_sizes, int n_in,
                              void* d_out, int out_size, void* d_ws, size_t ws_size,
                              hipStream_t stream) {
  const float* x       = (const float*)d_in[0];
  const float* Wc      = (const float*)d_in[1];
  const float* temp    = (const float*)d_in[2];
  const float* genes   = (const float*)d_in[3];
  const float* Wd      = (const float*)d_in[4];
  const float* Wu      = (const float*)d_in[5];
  const float* nw      = (const float*)d_in[6];
  const float* scale_p = (const float*)d_in[7];

  char* ws = (char*)d_ws;
  float* r_buf          = (float*)ws;                                   // 32 KB (64 KB reserved)
  unsigned short* xn_bf = (unsigned short*)(ws + 65536);                // 32 MB (free after k3)
  unsigned short* wc_bf = (unsigned short*)(ws + 65536 + (size_t)M_TOK * D_DIM * 2);   // 16 MB
  char* p = ws + 65536 + (size_t)M_TOK * D_DIM * 2 + (size_t)G_GENES * D_DIM * 2;
  int* cand    = (int*)p;                       p += (size_t)M_TOK * NCAND * 4;
  p += (size_t)M_TOK * NCAND * 8;               // (former cval slot, unused)
  unsigned short* e_hi = (unsigned short*)p;    p += (size_t)M_TOK * GD_DIM * 2;
  unsigned short* e_lo = (unsigned short*)p;

  // Wd/Wu bf16 hi/lo splits live in the xn_bf region (dead after k3): 4 x 1 MB
  unsigned short* wdh = (unsigned short*)(ws + 65536);
  unsigned short* wdl = wdh + (size_t)D_DIM * GD_DIM;
  unsigned short* wuh = wdl + (size_t)D_DIM * GD_DIM;
  unsigned short* wul = wuh + (size_t)D_DIM * GD_DIM;
  // fp64 partials also in the dead xn_bf region, after the 4 MB of splits:
  // 8192 x 8 x 40 x 8B = 21 MB (region holds 32 MB total)
  double* part = (double*)(ws + 65536 + 4ull * D_DIM * GD_DIM * 2);

  unsigned short* logits_bf = (unsigned short*)d_out;  // 33.5M bf16 == 64 MB == d_out

  k1_rmsnorm<<<dim3(M_TOK), dim3(256), 0, stream>>>(x, nw, r_buf, xn_bf);
  k2_cvt<<<dim3((G_GENES * D_DIM) / (256 * 8)), dim3(256), 0, stream>>>(Wc, wc_bf);
  k3_gemm_logits<<<dim3(G_GENES / 128, M_TOK / 128), dim3(256), 0, stream>>>(xn_bf, wc_bf, logits_bf);
  k4_topk<<<dim3(M_TOK / 4), dim3(256), 0, stream>>>(logits_bf, cand);
  k2b_split<<<dim3((D_DIM * GD_DIM) / (256 * 4), 2), dim3(256), 0, stream>>>(Wd, Wu, wdh, wdl, wuh, wul);
  k5a_partial<<<dim3(M_TOK), dim3(256), 0, stream>>>(x, r_buf, nw, Wc, cand, part);
  k6_express<<<dim3(M_TOK), dim3(256), 0, stream>>>(part, cand, genes, temp, e_hi, e_lo);
  k7_mfma<<<dim3(D_DIM / 64, M_TOK / 128), dim3(256), 0, stream>>>(e_hi, e_lo, wdh, wdl, wuh, wul,
                                                                   x, r_buf, nw, scale_p, (float*)d_out);
}

// Round 7
// 541.572 us; speedup vs baseline: 1.7121x; 1.2837x over previous
//
#include <hip/hip_runtime.h>
#include <math.h>

#define M_TOK 8192
#define D_DIM 2048
#define G_GENES 4096
#define GD_DIM 256
#define KSEL 32
#define NCAND 40
#define NSLICE 8

typedef float f32x4 __attribute__((ext_vector_type(4)));
typedef short bf16x8 __attribute__((ext_vector_type(8)));

__device__ __forceinline__ void async_copy16(const void* g, void* lds) {
  __builtin_amdgcn_global_load_lds((const __attribute__((address_space(1))) void*)g,
                                   (__attribute__((address_space(3))) void*)lds, 16, 0, 0);
}

__device__ __forceinline__ unsigned short f2bf(float f) {
  unsigned int u = __float_as_uint(f);
  unsigned int r = (u + 0x7fffu + ((u >> 16) & 1u)) >> 16;
  return (unsigned short)r;
}
__device__ __forceinline__ float bf2f(unsigned short h) {
  return __uint_as_float(((unsigned int)h) << 16);
}

// ---------------- K1: RMSNorm -> r[t], xn_bf16 ----------------
__global__ __launch_bounds__(256) void k1_rmsnorm(const float* __restrict__ x,
                                                  const float* __restrict__ nw,
                                                  float* __restrict__ r_out,
                                                  unsigned short* __restrict__ xn_bf) {
  int t = blockIdx.x, tid = threadIdx.x;
  const float4* xr = (const float4*)(x + (size_t)t * D_DIM);
  float4 a = xr[tid], b = xr[tid + 256];
  double ss = (double)a.x*a.x + (double)a.y*a.y + (double)a.z*a.z + (double)a.w*a.w
            + (double)b.x*b.x + (double)b.y*b.y + (double)b.z*b.z + (double)b.w*b.w;
  for (int off = 32; off; off >>= 1) ss += __shfl_down(ss, off);
  __shared__ double sred[4];
  __shared__ float rshare;
  int lane = tid & 63, wv = tid >> 6;
  if (lane == 0) sred[wv] = ss;
  __syncthreads();
  if (tid == 0) {
    double tot = sred[0] + sred[1] + sred[2] + sred[3];
    float r = (float)(1.0 / sqrt(tot / (double)D_DIM + 1.1920928955078125e-7));
    rshare = r; r_out[t] = r;
  }
  __syncthreads();
  float r = rshare;
  const float4* nw4 = (const float4*)nw;
  float4 na = nw4[tid], nb = nw4[tid + 256];
  ushort4 oa, ob;
  oa.x = f2bf(a.x * r * na.x); oa.y = f2bf(a.y * r * na.y);
  oa.z = f2bf(a.z * r * na.z); oa.w = f2bf(a.w * r * na.w);
  ob.x = f2bf(b.x * r * nb.x); ob.y = f2bf(b.y * r * nb.y);
  ob.z = f2bf(b.z * r * nb.z); ob.w = f2bf(b.w * r * nb.w);
  ushort4* o4 = (ushort4*)(xn_bf + (size_t)t * D_DIM);
  o4[tid] = oa; o4[tid + 256] = ob;
}

// ---------------- K2: Wc fp32 -> bf16 ----------------
__global__ __launch_bounds__(256) void k2_cvt(const float* __restrict__ w,
                                              unsigned short* __restrict__ wb) {
  size_t i = (size_t)blockIdx.x * 256 + threadIdx.x;   // handles 8 elements
  const float4* w4 = (const float4*)w;
  float4 a = w4[2*i], b = w4[2*i+1];
  ushort4 oa, ob;
  oa.x = f2bf(a.x); oa.y = f2bf(a.y); oa.z = f2bf(a.z); oa.w = f2bf(a.w);
  ob.x = f2bf(b.x); ob.y = f2bf(b.y); ob.z = f2bf(b.z); ob.w = f2bf(b.w);
  ((ushort4*)wb)[2*i] = oa; ((ushort4*)wb)[2*i+1] = ob;
}

// ---------------- K2b: split Wd/Wu into bf16 hi+lo ----------------
__global__ __launch_bounds__(256) void k2b_split(const float* __restrict__ wd,
                                                 const float* __restrict__ wu,
                                                 unsigned short* __restrict__ wdh,
                                                 unsigned short* __restrict__ wdl,
                                                 unsigned short* __restrict__ wuh,
                                                 unsigned short* __restrict__ wul) {
  const float* src = blockIdx.y ? wu : wd;
  unsigned short* dh = blockIdx.y ? wuh : wdh;
  unsigned short* dl = blockIdx.y ? wul : wdl;
  size_t i = (size_t)blockIdx.x * 256 + threadIdx.x;   // float4 index
  float4 v = ((const float4*)src)[i];
  ushort4 h, l;
  h.x = f2bf(v.x); l.x = f2bf(v.x - bf2f(h.x));
  h.y = f2bf(v.y); l.y = f2bf(v.y - bf2f(h.y));
  h.z = f2bf(v.z); l.z = f2bf(v.z - bf2f(h.z));
  h.w = f2bf(v.w); l.w = f2bf(v.w - bf2f(h.w));
  ((ushort4*)dh)[i] = h;
  ((ushort4*)dl)[i] = l;
}

// ---------------- K3: approx logits GEMM (bf16 MFMA, 128x128 tile) ----------------
__global__ __launch_bounds__(256) void k3_gemm_logits(const unsigned short* __restrict__ A,
                                                      const unsigned short* __restrict__ B,
                                                      unsigned short* __restrict__ C) {
  __shared__ unsigned short As[128 * 32];
  __shared__ unsigned short Bs[128 * 32];
  int tid = threadIdx.x;
  int lane = tid & 63, wv = tid >> 6;
  // bijective XCD swizzle over 2048 blocks (2048 % 8 == 0)
  int lin = blockIdx.y * gridDim.x + blockIdx.x;
  int swz = (lin & 7) * (2048 / 8) + (lin >> 3);
  int bn = swz & 31, bm = swz >> 5;
  int wr = wv >> 1, wc = wv & 1;
  f32x4 acc[4][4];
#pragma unroll
  for (int m = 0; m < 4; ++m)
#pragma unroll
    for (int n = 0; n < 4; ++n) acc[m][n] = (f32x4){0.f, 0.f, 0.f, 0.f};

  const int lrow = lane >> 2;
  const int lcol = (lane & 3) * 8;
  size_t abase = (size_t)(bm * 128) * D_DIM;
  size_t bbase = (size_t)(bn * 128) * D_DIM;

  for (int kt = 0; kt < D_DIM; kt += 32) {
    __syncthreads();
#pragma unroll
    for (int c = 0; c < 2; ++c) {
      int rr = (wv * 2 + c) * 16 + lrow;
      async_copy16(A + abase + (size_t)rr * D_DIM + kt + lcol, &As[(wv * 2 + c) * 512]);
      async_copy16(B + bbase + (size_t)rr * D_DIM + kt + lcol, &Bs[(wv * 2 + c) * 512]);
    }
    __syncthreads();
    bf16x8 fa[4], fb[4];
#pragma unroll
    for (int m = 0; m < 4; ++m)
      fa[m] = *(const bf16x8*)&As[(wr * 64 + m * 16 + (lane & 15)) * 32 + (lane >> 4) * 8];
#pragma unroll
    for (int n = 0; n < 4; ++n)
      fb[n] = *(const bf16x8*)&Bs[(wc * 64 + n * 16 + (lane & 15)) * 32 + (lane >> 4) * 8];
#pragma unroll
    for (int m = 0; m < 4; ++m)
#pragma unroll
      for (int n = 0; n < 4; ++n)
        acc[m][n] = __builtin_amdgcn_mfma_f32_16x16x32_bf16(fa[m], fb[n], acc[m][n], 0, 0, 0);
  }
#pragma unroll
  for (int m = 0; m < 4; ++m)
#pragma unroll
    for (int n = 0; n < 4; ++n)
#pragma unroll
      for (int j = 0; j < 4; ++j) {
        int row = bm * 128 + wr * 64 + m * 16 + (lane >> 4) * 4 + j;
        int col = bn * 128 + wc * 64 + n * 16 + (lane & 15);
        C[(size_t)row * G_GENES + col] = f2bf(acc[m][n][j]);
      }
}

// ---------------- K4: per-token top-40 via 16-bit radix threshold search ----------------
// bf16 -> monotone u16 key; 16-step binary search on key space for the rank-40
// threshold T (count(>=lo)>=40 > count(>=lo+1)), then deterministic
// ballot-prefix compaction: all keys > T, then keys == T filled to exactly 40.
// Same candidate SET as the iterative argmax, ~4x fewer VALU ops.
__global__ __launch_bounds__(256) void k4_topk(const unsigned short* __restrict__ L,
                                               int* __restrict__ cand) {
  int wv = threadIdx.x >> 6, lane = threadIdx.x & 63;
  int t = blockIdx.x * 4 + wv;
  const unsigned short* lp = L + (size_t)t * G_GENES;
  unsigned kp[32];
#pragma unroll
  for (int i = 0; i < 8; ++i) {
    uint4 raw = *(const uint4*)(lp + i * 512 + lane * 8);
    unsigned rr[4] = {raw.x, raw.y, raw.z, raw.w};
#pragma unroll
    for (int q = 0; q < 4; ++q) {
      unsigned r = rr[q];
      unsigned s = (r >> 15) & 0x00010001u;
      unsigned xm = 0x80008000u | (s * 0x7FFFu);   // per-half: sign? 0xFFFF : 0x8000
      kp[i * 4 + q] = r ^ xm;
    }
  }
  unsigned lo = 0, hi = 65536;
  while (hi - lo > 1u) {
    unsigned mid = (lo + hi) >> 1;
    int c = 0;
#pragma unroll
    for (int q = 0; q < 32; ++q) {
      c += __popcll(__ballot((kp[q] & 0xFFFFu) >= mid));
      c += __popcll(__ballot((kp[q] >> 16) >= mid));
    }
    if (c >= NCAND) lo = mid; else hi = mid;
  }
  const unsigned T = lo;
  unsigned long long below = (1ull << lane) - 1ull;
  int* outp = cand + (size_t)t * NCAND;
  int cnt = 0;
#pragma unroll
  for (int q = 0; q < 32; ++q) {
#pragma unroll
    for (int h = 0; h < 2; ++h) {
      unsigned key = h ? (kp[q] >> 16) : (kp[q] & 0xFFFFu);
      bool pred = key > T;
      unsigned long long m = __ballot(pred);
      if (pred) {
        int pos = cnt + (int)__popcll(m & below);
        outp[pos] = (q >> 2) * 512 + lane * 8 + (q & 3) * 2 + h;
      }
      cnt += (int)__popcll(m);
    }
  }
#pragma unroll 1
  for (int q = 0; q < 32 && cnt < NCAND; ++q) {
#pragma unroll
    for (int h = 0; h < 2; ++h) {
      unsigned key = h ? (kp[q] >> 16) : (kp[q] & 0xFFFFu);
      bool pred = key == T;
      unsigned long long m = __ballot(pred);
      if (pred) {
        int pos = cnt + (int)__popcll(m & below);
        if (pos < NCAND)
          outp[pos] = (q >> 2) * 512 + lane * 8 + (q & 3) * 2 + h;
      }
      cnt += (int)__popcll(m);
    }
  }
}

// ---------------- K5a: fp64 partial rescore, D-sliced, compress-tree reduce ----------------
__global__ __launch_bounds__(256) void k5a_partial(const float* __restrict__ x,
                                                   const float* __restrict__ r,
                                                   const float* __restrict__ nw,
                                                   const float* __restrict__ Wc,
                                                   const int* __restrict__ cand,
                                                   double* __restrict__ part) {
  int bid = blockIdx.x;
  int slice = bid & 7;
  int group = bid >> 3;
  int wv = threadIdx.x >> 6, lane = threadIdx.x & 63;
  const int dbase = slice * 256;
  float4 nv = *(const float4*)(nw + dbase + lane * 4);
  bool b0 = (lane & 1) != 0, b1 = (lane & 2) != 0, b2 = (lane & 4) != 0;
#pragma unroll 1
  for (int tt = 0; tt < 2; ++tt) {
    int t = group * 8 + wv * 2 + tt;
    float rr = r[t];
    float4 xv = *(const float4*)(x + (size_t)t * D_DIM + dbase + lane * 4);
    float4 xl;
    xl.x = xv.x * rr * nv.x;
    xl.y = xv.y * rr * nv.y;
    xl.z = xv.z * rr * nv.z;
    xl.w = xv.w * rr * nv.w;
    int myg = cand[t * NCAND + (lane < NCAND ? lane : 0)];
    double* outp = part + ((size_t)t * NSLICE + slice) * NCAND;
#pragma unroll 1
    for (int j0 = 0; j0 < NCAND; j0 += 8) {
      float4 w[8];
#pragma unroll
      for (int c = 0; c < 8; ++c) {
        int g = __shfl(myg, j0 + c);
        w[c] = *(const float4*)(Wc + (size_t)g * D_DIM + dbase + lane * 4);
      }
      double s[8];
#pragma unroll
      for (int c = 0; c < 8; ++c)
        s[c] = ((double)xl.x * (double)w[c].x + (double)xl.y * (double)w[c].y)
             + ((double)xl.z * (double)w[c].z + (double)xl.w * (double)w[c].w);
      // stage A (bit0): 8 -> 4 regs
      double u01 = b0 ? s[1] : s[0], t01 = b0 ? s[0] : s[1];
      double u23 = b0 ? s[3] : s[2], t23 = b0 ? s[2] : s[3];
      double u45 = b0 ? s[5] : s[4], t45 = b0 ? s[4] : s[5];
      double u67 = b0 ? s[7] : s[6], t67 = b0 ? s[6] : s[7];
      u01 += __shfl_xor(t01, 1);
      u23 += __shfl_xor(t23, 1);
      u45 += __shfl_xor(t45, 1);
      u67 += __shfl_xor(t67, 1);
      // stage B (bit1): 4 -> 2 regs
      double v03 = b1 ? u23 : u01, t03 = b1 ? u01 : u23;
      double v47 = b1 ? u67 : u45, t47 = b1 ? u45 : u67;
      v03 += __shfl_xor(t03, 2);
      v47 += __shfl_xor(t47, 2);
      // stage C (bit2): 2 -> 1 reg; lane l holds candidate (l&7) group-sum
      double wsum = b2 ? v47 : v03, t07 = b2 ? v03 : v47;
      wsum += __shfl_xor(t07, 4);
      // stages D-F: reduce across 8-lane groups
      wsum += __shfl_xor(wsum, 8);
      wsum += __shfl_xor(wsum, 16);
      wsum += __shfl_xor(wsum, 32);
      if (lane < 8) outp[j0 + lane] = wsum;
    }
  }
}

// ---------------- K6: sum partials, select top-32, softmax, combine ----------------
__global__ __launch_bounds__(256) void k6_express(const double* __restrict__ part,
                                                  const int* __restrict__ cand,
                                                  const float* __restrict__ genes,
                                                  const float* __restrict__ temp,
                                                  unsigned short* __restrict__ e_hi,
                                                  unsigned short* __restrict__ e_lo) {
  int t = blockIdx.x, tid = threadIdx.x;
  __shared__ double sval[NCAND];
  __shared__ int sidx[NCAND];
  __shared__ float sw[NCAND];
  float tclamp = fmaxf(temp[0], 0.1f);
  if (tid < NCAND) {
    const double* pp = part + (size_t)t * NSLICE * NCAND + tid;
    double v = 0.0;
#pragma unroll
    for (int s = 0; s < NSLICE; ++s) v += pp[s * NCAND];
    sval[tid] = v / (double)tclamp;
    sidx[tid] = cand[(size_t)t * NCAND + tid];
  }
  __syncthreads();
  if (tid < 64) {
    double v = (tid < NCAND) ? sval[tid] : -1.0e300;
    int gi = (tid < NCAND) ? sidx[tid] : 0x7fffffff;
    int rank = 0;
    for (int j = 0; j < NCAND; ++j) {
      double vj = sval[j]; int gj = sidx[j];
      if (vj > v || (vj == v && gj < gi)) rank++;
    }
    bool sel = (tid < NCAND) && (rank < KSEL);
    double vs = sel ? v : -1.0e300;
    double mx = vs;
    for (int off = 32; off; off >>= 1) { double o = __shfl_xor(mx, off); mx = fmax(mx, o); }
    double e = sel ? exp(v - mx) : 0.0;
    double ssum = e;
    for (int off = 32; off; off >>= 1) ssum += __shfl_xor(ssum, off);
    if (tid < NCAND) sw[tid] = (float)(e / ssum);
  }
  __syncthreads();
  float a0 = 0.f, a1 = 0.f, a2 = 0.f, a3 = 0.f;
#pragma unroll
  for (int k = 0; k < NCAND; k += 4) {
    a0 += sw[k]     * genes[(size_t)sidx[k]     * GD_DIM + tid];
    a1 += sw[k + 1] * genes[(size_t)sidx[k + 1] * GD_DIM + tid];
    a2 += sw[k + 2] * genes[(size_t)sidx[k + 2] * GD_DIM + tid];
    a3 += sw[k + 3] * genes[(size_t)sidx[k + 3] * GD_DIM + tid];
  }
  float acc = (a0 + a1) + (a2 + a3);
  unsigned short h = f2bf(acc);
  unsigned short l = f2bf(acc - bf2f(h));
  e_hi[(size_t)t * GD_DIM + tid] = h;
  e_lo[(size_t)t * GD_DIM + tid] = l;
}

// ---------------- K7: bf16-split MFMA down/up GEMM + tanh + xn + scale -> out ----------------
__global__ __launch_bounds__(256) void k7_mfma(const unsigned short* __restrict__ e_hi,
                                               const unsigned short* __restrict__ e_lo,
                                               const unsigned short* __restrict__ wdh,
                                               const unsigned short* __restrict__ wdl,
                                               const unsigned short* __restrict__ wuh,
                                               const unsigned short* __restrict__ wul,
                                               const float* __restrict__ x,
                                               const float* __restrict__ r,
                                               const float* __restrict__ nw,
                                               const float* __restrict__ scale_p,
                                               float* __restrict__ out) {
  __shared__ unsigned short Ah[128 * 32], Al[128 * 32];
  __shared__ unsigned short Dh[64 * 32], Dl[64 * 32], Uh[64 * 32], Ul[64 * 32];
  int tid = threadIdx.x;
  int lane = tid & 63, wv = tid >> 6;
  int bn = blockIdx.x, bm = blockIdx.y;
  int wr = wv >> 1, wc = wv & 1;   // wave tile: 64(M) x 32(N)
  const int lrow = lane >> 2;
  const int lcol = (lane & 3) * 8;

  f32x4 accD[4][2], accU[4][2];
#pragma unroll
  for (int m = 0; m < 4; ++m)
#pragma unroll
    for (int n = 0; n < 2; ++n) {
      accD[m][n] = (f32x4){0.f, 0.f, 0.f, 0.f};
      accU[m][n] = (f32x4){0.f, 0.f, 0.f, 0.f};
    }

  for (int kt = 0; kt < GD_DIM; kt += 32) {
    __syncthreads();
#pragma unroll
    for (int c = 0; c < 8; ++c) {
      int cid = wv * 8 + c;
      if (cid < 8) {
        async_copy16(e_hi + (size_t)(bm * 128 + cid * 16 + lrow) * GD_DIM + kt + lcol,
                     &Ah[cid * 512]);
      } else if (cid < 16) {
        int cc = cid - 8;
        async_copy16(e_lo + (size_t)(bm * 128 + cc * 16 + lrow) * GD_DIM + kt + lcol,
                     &Al[cc * 512]);
      } else if (cid < 20) {
        int cc = cid - 16;
        async_copy16(wdh + (size_t)(bn * 64 + cc * 16 + lrow) * GD_DIM + kt + lcol,
                     &Dh[cc * 512]);
      } else if (cid < 24) {
        int cc = cid - 20;
        async_copy16(wdl + (size_t)(bn * 64 + cc * 16 + lrow) * GD_DIM + kt + lcol,
                     &Dl[cc * 512]);
      } else if (cid < 28) {
        int cc = cid - 24;
        async_copy16(wuh + (size_t)(bn * 64 + cc * 16 + lrow) * GD_DIM + kt + lcol,
                     &Uh[cc * 512]);
      } else {
        int cc = cid - 28;
        async_copy16(wul + (size_t)(bn * 64 + cc * 16 + lrow) * GD_DIM + kt + lcol,
                     &Ul[cc * 512]);
      }
    }
    __syncthreads();
    bf16x8 fah[4], fal[4], fdh[2], fdl[2], fuh[2], ful[2];
#pragma unroll
    for (int m = 0; m < 4; ++m) {
      int off = (wr * 64 + m * 16 + (lane & 15)) * 32 + (lane >> 4) * 8;
      fah[m] = *(const bf16x8*)&Ah[off];
      fal[m] = *(const bf16x8*)&Al[off];
    }
#pragma unroll
    for (int n = 0; n < 2; ++n) {
      int off = (wc * 32 + n * 16 + (lane & 15)) * 32 + (lane >> 4) * 8;
      fdh[n] = *(const bf16x8*)&Dh[off];
      fdl[n] = *(const bf16x8*)&Dl[off];
      fuh[n] = *(const bf16x8*)&Uh[off];
      ful[n] = *(const bf16x8*)&Ul[off];
    }
#pragma unroll
    for (int m = 0; m < 4; ++m)
#pragma unroll
      for (int n = 0; n < 2; ++n) {
        accD[m][n] = __builtin_amdgcn_mfma_f32_16x16x32_bf16(fah[m], fdh[n], accD[m][n], 0, 0, 0);
        accD[m][n] = __builtin_amdgcn_mfma_f32_16x16x32_bf16(fah[m], fdl[n], accD[m][n], 0, 0, 0);
        accD[m][n] = __builtin_amdgcn_mfma_f32_16x16x32_bf16(fal[m], fdh[n], accD[m][n], 0, 0, 0);
        accU[m][n] = __builtin_amdgcn_mfma_f32_16x16x32_bf16(fah[m], fuh[n], accU[m][n], 0, 0, 0);
        accU[m][n] = __builtin_amdgcn_mfma_f32_16x16x32_bf16(fah[m], ful[n], accU[m][n], 0, 0, 0);
        accU[m][n] = __builtin_amdgcn_mfma_f32_16x16x32_bf16(fal[m], fuh[n], accU[m][n], 0, 0, 0);
      }
  }
  float sc = scale_p[0];
#pragma unroll
  for (int m = 0; m < 4; ++m)
#pragma unroll
    for (int j = 0; j < 4; ++j) {
      int token = bm * 128 + wr * 64 + m * 16 + (lane >> 4) * 4 + j;
      float rr = r[token];
#pragma unroll
      for (int n = 0; n < 2; ++n) {
        int d = bn * 64 + wc * 32 + n * 16 + (lane & 15);
        float xn = x[(size_t)token * D_DIM + d] * rr * nw[d];
        out[(size_t)token * D_DIM + d] = tanhf(accD[m][n][j]) * xn * accU[m][n][j] * sc;
      }
    }
}

extern "C" void kernel_launch(void* const* d_in, const int* in_sizes, int n_in,
                              void* d_out, int out_size, void* d_ws, size_t ws_size,
                              hipStream_t stream) {
  const float* x       = (const float*)d_in[0];
  const float* Wc      = (const float*)d_in[1];
  const float* temp    = (const float*)d_in[2];
  const float* genes   = (const float*)d_in[3];
  const float* Wd      = (const float*)d_in[4];
  const float* Wu      = (const float*)d_in[5];
  const float* nw      = (const float*)d_in[6];
  const float* scale_p = (const float*)d_in[7];

  char* ws = (char*)d_ws;
  float* r_buf          = (float*)ws;                                   // 32 KB (64 KB reserved)
  unsigned short* xn_bf = (unsigned short*)(ws + 65536);                // 32 MB (free after k3)
  unsigned short* wc_bf = (unsigned short*)(ws + 65536 + (size_t)M_TOK * D_DIM * 2);   // 16 MB
  char* p = ws + 65536 + (size_t)M_TOK * D_DIM * 2 + (size_t)G_GENES * D_DIM * 2;
  int* cand    = (int*)p;                       p += (size_t)M_TOK * NCAND * 4;
  p += (size_t)M_TOK * NCAND * 8;               // (former cval slot, unused)
  unsigned short* e_hi = (unsigned short*)p;    p += (size_t)M_TOK * GD_DIM * 2;
  unsigned short* e_lo = (unsigned short*)p;

  // Wd/Wu bf16 hi/lo splits live in the xn_bf region (dead after k3): 4 x 1 MB
  unsigned short* wdh = (unsigned short*)(ws + 65536);
  unsigned short* wdl = wdh + (size_t)D_DIM * GD_DIM;
  unsigned short* wuh = wdl + (size_t)D_DIM * GD_DIM;
  unsigned short* wul = wuh + (size_t)D_DIM * GD_DIM;
  // fp64 partials also in the dead xn_bf region, after the 4 MB of splits:
  // 8192 x 8 x 40 x 8B = 21 MB (region holds 32 MB total)
  double* part = (double*)(ws + 65536 + 4ull * D_DIM * GD_DIM * 2);

  unsigned short* logits_bf = (unsigned short*)d_out;  // 33.5M bf16 == 64 MB == d_out

  k1_rmsnorm<<<dim3(M_TOK), dim3(256), 0, stream>>>(x, nw, r_buf, xn_bf);
  k2_cvt<<<dim3((G_GENES * D_DIM) / (256 * 8)), dim3(256), 0, stream>>>(Wc, wc_bf);
  k3_gemm_logits<<<dim3(G_GENES / 128, M_TOK / 128), dim3(256), 0, stream>>>(xn_bf, wc_bf, logits_bf);
  k4_topk<<<dim3(M_TOK / 4), dim3(256), 0, stream>>>(logits_bf, cand);
  k2b_split<<<dim3((D_DIM * GD_DIM) / (256 * 4), 2), dim3(256), 0, stream>>>(Wd, Wu, wdh, wdl, wuh, wul);
  k5a_partial<<<dim3(M_TOK), dim3(256), 0, stream>>>(x, r_buf, nw, Wc, cand, part);
  k6_express<<<dim3(M_TOK), dim3(256), 0, stream>>>(part, cand, genes, temp, e_hi, e_lo);
  k7_mfma<<<dim3(D_DIM / 64, M_TOK / 128), dim3(256), 0, stream>>>(e_hi, e_lo, wdh, wdl, wuh, wul,
                                                                   x, r_buf, nw, scale_p, (float*)d_out);
}

// Round 8
// 523.648 us; speedup vs baseline: 1.7707x; 1.0342x over previous
//
#include <hip/hip_runtime.h>
#include <math.h>

#define M_TOK 8192
#define D_DIM 2048
#define G_GENES 4096
#define GD_DIM 256
#define KSEL 32
#define NCAND 40
#define NSLICE 8

typedef float f32x4 __attribute__((ext_vector_type(4)));
typedef short bf16x8 __attribute__((ext_vector_type(8)));

__device__ __forceinline__ void async_copy16(const void* g, void* lds) {
  __builtin_amdgcn_global_load_lds((const __attribute__((address_space(1))) void*)g,
                                   (__attribute__((address_space(3))) void*)lds, 16, 0, 0);
}

__device__ __forceinline__ unsigned short f2bf(float f) {
  unsigned int u = __float_as_uint(f);
  unsigned int r = (u + 0x7fffu + ((u >> 16) & 1u)) >> 16;
  return (unsigned short)r;
}
__device__ __forceinline__ float bf2f(unsigned short h) {
  return __uint_as_float(((unsigned int)h) << 16);
}

// ---------------- K1: RMSNorm -> r[t], xn_bf16 ----------------
__global__ __launch_bounds__(256) void k1_rmsnorm(const float* __restrict__ x,
                                                  const float* __restrict__ nw,
                                                  float* __restrict__ r_out,
                                                  unsigned short* __restrict__ xn_bf) {
  int t = blockIdx.x, tid = threadIdx.x;
  const float4* xr = (const float4*)(x + (size_t)t * D_DIM);
  float4 a = xr[tid], b = xr[tid + 256];
  double ss = (double)a.x*a.x + (double)a.y*a.y + (double)a.z*a.z + (double)a.w*a.w
            + (double)b.x*b.x + (double)b.y*b.y + (double)b.z*b.z + (double)b.w*b.w;
  for (int off = 32; off; off >>= 1) ss += __shfl_down(ss, off);
  __shared__ double sred[4];
  __shared__ float rshare;
  int lane = tid & 63, wv = tid >> 6;
  if (lane == 0) sred[wv] = ss;
  __syncthreads();
  if (tid == 0) {
    double tot = sred[0] + sred[1] + sred[2] + sred[3];
    float r = (float)(1.0 / sqrt(tot / (double)D_DIM + 1.1920928955078125e-7));
    rshare = r; r_out[t] = r;
  }
  __syncthreads();
  float r = rshare;
  const float4* nw4 = (const float4*)nw;
  float4 na = nw4[tid], nb = nw4[tid + 256];
  ushort4 oa, ob;
  oa.x = f2bf(a.x * r * na.x); oa.y = f2bf(a.y * r * na.y);
  oa.z = f2bf(a.z * r * na.z); oa.w = f2bf(a.w * r * na.w);
  ob.x = f2bf(b.x * r * nb.x); ob.y = f2bf(b.y * r * nb.y);
  ob.z = f2bf(b.z * r * nb.z); ob.w = f2bf(b.w * r * nb.w);
  ushort4* o4 = (ushort4*)(xn_bf + (size_t)t * D_DIM);
  o4[tid] = oa; o4[tid + 256] = ob;
}

// ---------------- K2: Wc fp32 -> bf16 ----------------
__global__ __launch_bounds__(256) void k2_cvt(const float* __restrict__ w,
                                              unsigned short* __restrict__ wb) {
  size_t i = (size_t)blockIdx.x * 256 + threadIdx.x;   // handles 8 elements
  const float4* w4 = (const float4*)w;
  float4 a = w4[2*i], b = w4[2*i+1];
  ushort4 oa, ob;
  oa.x = f2bf(a.x); oa.y = f2bf(a.y); oa.z = f2bf(a.z); oa.w = f2bf(a.w);
  ob.x = f2bf(b.x); ob.y = f2bf(b.y); ob.z = f2bf(b.z); ob.w = f2bf(b.w);
  ((ushort4*)wb)[2*i] = oa; ((ushort4*)wb)[2*i+1] = ob;
}

// ---------------- K2b: split Wd/Wu into bf16 hi+lo ----------------
__global__ __launch_bounds__(256) void k2b_split(const float* __restrict__ wd,
                                                 const float* __restrict__ wu,
                                                 unsigned short* __restrict__ wdh,
                                                 unsigned short* __restrict__ wdl,
                                                 unsigned short* __restrict__ wuh,
                                                 unsigned short* __restrict__ wul) {
  const float* src = blockIdx.y ? wu : wd;
  unsigned short* dh = blockIdx.y ? wuh : wdh;
  unsigned short* dl = blockIdx.y ? wul : wdl;
  size_t i = (size_t)blockIdx.x * 256 + threadIdx.x;   // float4 index
  float4 v = ((const float4*)src)[i];
  ushort4 h, l;
  h.x = f2bf(v.x); l.x = f2bf(v.x - bf2f(h.x));
  h.y = f2bf(v.y); l.y = f2bf(v.y - bf2f(h.y));
  h.z = f2bf(v.z); l.z = f2bf(v.z - bf2f(h.z));
  h.w = f2bf(v.w); l.w = f2bf(v.w - bf2f(h.w));
  ((ushort4*)dh)[i] = h;
  ((ushort4*)dl)[i] = l;
}

// ---------------- K3: logits GEMM, 256x256 tile, 8-wave, phase-split + counted vmcnt ----------------
// C[8192][4096] = A[8192][2048] * B[4096][2048]^T, all bf16 (K-contiguous).
// BK=32, 4-deep LDS ring (stage 3 K-tiles ahead), 2 phases/K-tile:
//   {8x ds_read_b128 | 2x global_load_lds -> barrier -> lgkmcnt(0) -> setprio(1) 16 MFMA setprio(0) -> barrier}
// vmcnt(8) once per K-tile (never 0 in main loop).
// LDS XOR swizzle slot^=(row>>1)&3 applied BOTH sides: pre-swizzled global src
// (gload_lds writes linearly) + swizzled ds_read -> each 16-lane quarter is
// 2-way bank-aliased (free). Accumulation order identical to previous k3.
__global__ __launch_bounds__(512, 1) void k3_gemm_logits(const unsigned short* __restrict__ A,
                                                         const unsigned short* __restrict__ B,
                                                         unsigned short* __restrict__ C) {
  __shared__ unsigned short As[4][256 * 32];
  __shared__ unsigned short Bs[4][256 * 32];
  const int tid = threadIdx.x;
  const int lane = tid & 63, wv = tid >> 6;
  const int wm = wv >> 2, wn = wv & 3;       // wave tile: 128(M) x 64(N)
  // XCD swizzle over 512 blocks (512 % 8 == 0), bm-fastest for B-panel L2 residency
  int lin = blockIdx.x;
  int swz = (lin & 7) * 64 + (lin >> 3);
  const int bm = swz & 31, bn = swz >> 5;

  // staging constants: wave wv stages rows [wv*32, wv*32+32) of both A and B tiles
  const int grow = lane >> 2;                          // 0..15 within 16-row issue
  const int gslot = (lane & 3) ^ ((lane >> 3) & 3);    // pre-swizzled global slot
  const unsigned short* agp = A + (size_t)(bm * 256 + wv * 32 + grow) * D_DIM + gslot * 8;
  const unsigned short* bgp = B + (size_t)(bn * 256 + wv * 32 + grow) * D_DIM + gslot * 8;
  // fragment-read constants
  const int fr = lane & 15;
  const int sw8 = (((lane >> 4) ^ ((lane >> 1) & 3))) * 8;  // swizzled 16B slot * 8 ushorts

  f32x4 acc[8][4];
#pragma unroll
  for (int m = 0; m < 8; ++m)
#pragma unroll
    for (int n = 0; n < 4; ++n) acc[m][n] = (f32x4){0.f, 0.f, 0.f, 0.f};

#define STAGE_A3(t_) { const int b_ = (t_) & 3; const int kt_ = (t_) * 32;          \
    async_copy16(agp + kt_,              &As[b_][(wv * 32) * 32]);                   \
    async_copy16(agp + kt_ + 16 * D_DIM, &As[b_][(wv * 32 + 16) * 32]); }
#define STAGE_B3(t_) { const int b_ = (t_) & 3; const int kt_ = (t_) * 32;          \
    async_copy16(bgp + kt_,              &Bs[b_][(wv * 32) * 32]);                   \
    async_copy16(bgp + kt_ + 16 * D_DIM, &Bs[b_][(wv * 32 + 16) * 32]); }

  // prologue: stage K-tiles 0,1,2 (12 issues); wait tile0 (keep 8 in flight)
  STAGE_A3(0); STAGE_B3(0);
  STAGE_A3(1); STAGE_B3(1);
  STAGE_A3(2); STAGE_B3(2);
  asm volatile("s_waitcnt vmcnt(8)" ::: "memory");
  __builtin_amdgcn_s_barrier();

#pragma unroll 1
  for (int t = 0; t < 64; ++t) {
    const int c = t & 3;
    const unsigned short* as = As[c];
    const unsigned short* bs = Bs[c];
    bf16x8 fa[4], fb[4];
    // ---- phase 1: quadrant m0..3 x n0..3 ----
#pragma unroll
    for (int n = 0; n < 4; ++n)
      fb[n] = *(const bf16x8*)&bs[(wn * 64 + n * 16 + fr) * 32 + sw8];
#pragma unroll
    for (int m = 0; m < 4; ++m)
      fa[m] = *(const bf16x8*)&as[(wm * 128 + m * 16 + fr) * 32 + sw8];
    if (t + 3 < 64) STAGE_A3(t + 3);
    __builtin_amdgcn_s_barrier();
    asm volatile("s_waitcnt lgkmcnt(0)" ::: "memory");
    __builtin_amdgcn_sched_barrier(0);
    __builtin_amdgcn_s_setprio(1);
#pragma unroll
    for (int m = 0; m < 4; ++m)
#pragma unroll
      for (int n = 0; n < 4; ++n)
        acc[m][n] = __builtin_amdgcn_mfma_f32_16x16x32_bf16(fa[m], fb[n], acc[m][n], 0, 0, 0);
    __builtin_amdgcn_s_setprio(0);
    __builtin_amdgcn_s_barrier();
    // ---- phase 2: quadrant m4..7 x n0..3 (fb reused) ----
#pragma unroll
    for (int m = 0; m < 4; ++m)
      fa[m] = *(const bf16x8*)&as[(wm * 128 + 64 + m * 16 + fr) * 32 + sw8];
    if (t + 3 < 64) STAGE_B3(t + 3);
    __builtin_amdgcn_s_barrier();
    asm volatile("s_waitcnt lgkmcnt(0)" ::: "memory");
    __builtin_amdgcn_sched_barrier(0);
    __builtin_amdgcn_s_setprio(1);
#pragma unroll
    for (int m = 0; m < 4; ++m)
#pragma unroll
      for (int n = 0; n < 4; ++n)
        acc[m + 4][n] = __builtin_amdgcn_mfma_f32_16x16x32_bf16(fa[m], fb[n], acc[m + 4][n], 0, 0, 0);
    __builtin_amdgcn_s_setprio(0);
    // end of K-tile: ensure tile t+1 resident before next iteration (counted, never 0 mid-loop)
    if (t <= 60)      { asm volatile("s_waitcnt vmcnt(8)" ::: "memory"); }
    else if (t == 61) { asm volatile("s_waitcnt vmcnt(4)" ::: "memory"); }
    else if (t == 62) { asm volatile("s_waitcnt vmcnt(0)" ::: "memory"); }
    __builtin_amdgcn_s_barrier();
  }
#undef STAGE_A3
#undef STAGE_B3

#pragma unroll
  for (int m = 0; m < 8; ++m)
#pragma unroll
    for (int n = 0; n < 4; ++n)
#pragma unroll
      for (int j = 0; j < 4; ++j) {
        int row = bm * 256 + wm * 128 + m * 16 + (lane >> 4) * 4 + j;
        int col = bn * 256 + wn * 64 + n * 16 + fr;
        C[(size_t)row * G_GENES + col] = f2bf(acc[m][n][j]);
      }
}

// ---------------- K4: per-token top-40 via 16-bit radix threshold search ----------------
__global__ __launch_bounds__(256) void k4_topk(const unsigned short* __restrict__ L,
                                               int* __restrict__ cand) {
  int wv = threadIdx.x >> 6, lane = threadIdx.x & 63;
  int t = blockIdx.x * 4 + wv;
  const unsigned short* lp = L + (size_t)t * G_GENES;
  unsigned kp[32];
#pragma unroll
  for (int i = 0; i < 8; ++i) {
    uint4 raw = *(const uint4*)(lp + i * 512 + lane * 8);
    unsigned rr[4] = {raw.x, raw.y, raw.z, raw.w};
#pragma unroll
    for (int q = 0; q < 4; ++q) {
      unsigned r = rr[q];
      unsigned s = (r >> 15) & 0x00010001u;
      unsigned xm = 0x80008000u | (s * 0x7FFFu);   // per-half: sign? 0xFFFF : 0x8000
      kp[i * 4 + q] = r ^ xm;
    }
  }
  unsigned lo = 0, hi = 65536;
  while (hi - lo > 1u) {
    unsigned mid = (lo + hi) >> 1;
    int c = 0;
#pragma unroll
    for (int q = 0; q < 32; ++q) {
      c += __popcll(__ballot((kp[q] & 0xFFFFu) >= mid));
      c += __popcll(__ballot((kp[q] >> 16) >= mid));
    }
    if (c >= NCAND) lo = mid; else hi = mid;
  }
  const unsigned T = lo;
  unsigned long long below = (1ull << lane) - 1ull;
  int* outp = cand + (size_t)t * NCAND;
  int cnt = 0;
#pragma unroll
  for (int q = 0; q < 32; ++q) {
#pragma unroll
    for (int h = 0; h < 2; ++h) {
      unsigned key = h ? (kp[q] >> 16) : (kp[q] & 0xFFFFu);
      bool pred = key > T;
      unsigned long long m = __ballot(pred);
      if (pred) {
        int pos = cnt + (int)__popcll(m & below);
        outp[pos] = (q >> 2) * 512 + lane * 8 + (q & 3) * 2 + h;
      }
      cnt += (int)__popcll(m);
    }
  }
#pragma unroll 1
  for (int q = 0; q < 32 && cnt < NCAND; ++q) {
#pragma unroll
    for (int h = 0; h < 2; ++h) {
      unsigned key = h ? (kp[q] >> 16) : (kp[q] & 0xFFFFu);
      bool pred = key == T;
      unsigned long long m = __ballot(pred);
      if (pred) {
        int pos = cnt + (int)__popcll(m & below);
        if (pos < NCAND)
          outp[pos] = (q >> 2) * 512 + lane * 8 + (q & 3) * 2 + h;
      }
      cnt += (int)__popcll(m);
    }
  }
}

// ---------------- K5a: fp64 partial rescore, D-sliced, compress-tree reduce ----------------
__global__ __launch_bounds__(256) void k5a_partial(const float* __restrict__ x,
                                                   const float* __restrict__ r,
                                                   const float* __restrict__ nw,
                                                   const float* __restrict__ Wc,
                                                   const int* __restrict__ cand,
                                                   double* __restrict__ part) {
  int bid = blockIdx.x;
  int slice = bid & 7;
  int group = bid >> 3;
  int wv = threadIdx.x >> 6, lane = threadIdx.x & 63;
  const int dbase = slice * 256;
  float4 nv = *(const float4*)(nw + dbase + lane * 4);
  bool b0 = (lane & 1) != 0, b1 = (lane & 2) != 0, b2 = (lane & 4) != 0;
#pragma unroll 1
  for (int tt = 0; tt < 2; ++tt) {
    int t = group * 8 + wv * 2 + tt;
    float rr = r[t];
    float4 xv = *(const float4*)(x + (size_t)t * D_DIM + dbase + lane * 4);
    float4 xl;
    xl.x = xv.x * rr * nv.x;
    xl.y = xv.y * rr * nv.y;
    xl.z = xv.z * rr * nv.z;
    xl.w = xv.w * rr * nv.w;
    int myg = cand[t * NCAND + (lane < NCAND ? lane : 0)];
    double* outp = part + ((size_t)t * NSLICE + slice) * NCAND;
#pragma unroll 1
    for (int j0 = 0; j0 < NCAND; j0 += 8) {
      float4 w[8];
#pragma unroll
      for (int c = 0; c < 8; ++c) {
        int g = __shfl(myg, j0 + c);
        w[c] = *(const float4*)(Wc + (size_t)g * D_DIM + dbase + lane * 4);
      }
      double s[8];
#pragma unroll
      for (int c = 0; c < 8; ++c)
        s[c] = ((double)xl.x * (double)w[c].x + (double)xl.y * (double)w[c].y)
             + ((double)xl.z * (double)w[c].z + (double)xl.w * (double)w[c].w);
      // stage A (bit0): 8 -> 4 regs
      double u01 = b0 ? s[1] : s[0], t01 = b0 ? s[0] : s[1];
      double u23 = b0 ? s[3] : s[2], t23 = b0 ? s[2] : s[3];
      double u45 = b0 ? s[5] : s[4], t45 = b0 ? s[4] : s[5];
      double u67 = b0 ? s[7] : s[6], t67 = b0 ? s[6] : s[7];
      u01 += __shfl_xor(t01, 1);
      u23 += __shfl_xor(t23, 1);
      u45 += __shfl_xor(t45, 1);
      u67 += __shfl_xor(t67, 1);
      // stage B (bit1): 4 -> 2 regs
      double v03 = b1 ? u23 : u01, t03 = b1 ? u01 : u23;
      double v47 = b1 ? u67 : u45, t47 = b1 ? u45 : u67;
      v03 += __shfl_xor(t03, 2);
      v47 += __shfl_xor(t47, 2);
      // stage C (bit2): 2 -> 1 reg; lane l holds candidate (l&7) group-sum
      double wsum = b2 ? v47 : v03, t07 = b2 ? v03 : v47;
      wsum += __shfl_xor(t07, 4);
      // stages D-F: reduce across 8-lane groups
      wsum += __shfl_xor(wsum, 8);
      wsum += __shfl_xor(wsum, 16);
      wsum += __shfl_xor(wsum, 32);
      if (lane < 8) outp[j0 + lane] = wsum;
    }
  }
}

// ---------------- K6: sum partials, select top-32, softmax, combine ----------------
__global__ __launch_bounds__(256) void k6_express(const double* __restrict__ part,
                                                  const int* __restrict__ cand,
                                                  const float* __restrict__ genes,
                                                  const float* __restrict__ temp,
                                                  unsigned short* __restrict__ e_hi,
                                                  unsigned short* __restrict__ e_lo) {
  int t = blockIdx.x, tid = threadIdx.x;
  __shared__ double sval[NCAND];
  __shared__ int sidx[NCAND];
  __shared__ float sw[NCAND];
  float tclamp = fmaxf(temp[0], 0.1f);
  if (tid < NCAND) {
    const double* pp = part + (size_t)t * NSLICE * NCAND + tid;
    double v = 0.0;
#pragma unroll
    for (int s = 0; s < NSLICE; ++s) v += pp[s * NCAND];
    sval[tid] = v / (double)tclamp;
    sidx[tid] = cand[(size_t)t * NCAND + tid];
  }
  __syncthreads();
  if (tid < 64) {
    double v = (tid < NCAND) ? sval[tid] : -1.0e300;
    int gi = (tid < NCAND) ? sidx[tid] : 0x7fffffff;
    int rank = 0;
    for (int j = 0; j < NCAND; ++j) {
      double vj = sval[j]; int gj = sidx[j];
      if (vj > v || (vj == v && gj < gi)) rank++;
    }
    bool sel = (tid < NCAND) && (rank < KSEL);
    double vs = sel ? v : -1.0e300;
    double mx = vs;
    for (int off = 32; off; off >>= 1) { double o = __shfl_xor(mx, off); mx = fmax(mx, o); }
    double e = sel ? exp(v - mx) : 0.0;
    double ssum = e;
    for (int off = 32; off; off >>= 1) ssum += __shfl_xor(ssum, off);
    if (tid < NCAND) sw[tid] = (float)(e / ssum);
  }
  __syncthreads();
  float a0 = 0.f, a1 = 0.f, a2 = 0.f, a3 = 0.f;
#pragma unroll
  for (int k = 0; k < NCAND; k += 4) {
    a0 += sw[k]     * genes[(size_t)sidx[k]     * GD_DIM + tid];
    a1 += sw[k + 1] * genes[(size_t)sidx[k + 1] * GD_DIM + tid];
    a2 += sw[k + 2] * genes[(size_t)sidx[k + 2] * GD_DIM + tid];
    a3 += sw[k + 3] * genes[(size_t)sidx[k + 3] * GD_DIM + tid];
  }
  float acc = (a0 + a1) + (a2 + a3);
  unsigned short h = f2bf(acc);
  unsigned short l = f2bf(acc - bf2f(h));
  e_hi[(size_t)t * GD_DIM + tid] = h;
  e_lo[(size_t)t * GD_DIM + tid] = l;
}

// ---------------- K7: bf16-split MFMA down/up GEMM + tanh + xn + scale -> out ----------------
__global__ __launch_bounds__(256) void k7_mfma(const unsigned short* __restrict__ e_hi,
                                               const unsigned short* __restrict__ e_lo,
                                               const unsigned short* __restrict__ wdh,
                                               const unsigned short* __restrict__ wdl,
                                               const unsigned short* __restrict__ wuh,
                                               const unsigned short* __restrict__ wul,
                                               const float* __restrict__ x,
                                               const float* __restrict__ r,
                                               const float* __restrict__ nw,
                                               const float* __restrict__ scale_p,
                                               float* __restrict__ out) {
  __shared__ unsigned short Ah[128 * 32], Al[128 * 32];
  __shared__ unsigned short Dh[64 * 32], Dl[64 * 32], Uh[64 * 32], Ul[64 * 32];
  int tid = threadIdx.x;
  int lane = tid & 63, wv = tid >> 6;
  int bn = blockIdx.x, bm = blockIdx.y;
  int wr = wv >> 1, wc = wv & 1;   // wave tile: 64(M) x 32(N)
  const int lrow = lane >> 2;
  const int lcol = (lane & 3) * 8;

  f32x4 accD[4][2], accU[4][2];
#pragma unroll
  for (int m = 0; m < 4; ++m)
#pragma unroll
    for (int n = 0; n < 2; ++n) {
      accD[m][n] = (f32x4){0.f, 0.f, 0.f, 0.f};
      accU[m][n] = (f32x4){0.f, 0.f, 0.f, 0.f};
    }

  for (int kt = 0; kt < GD_DIM; kt += 32) {
    __syncthreads();
#pragma unroll
    for (int c = 0; c < 8; ++c) {
      int cid = wv * 8 + c;
      if (cid < 8) {
        async_copy16(e_hi + (size_t)(bm * 128 + cid * 16 + lrow) * GD_DIM + kt + lcol,
                     &Ah[cid * 512]);
      } else if (cid < 16) {
        int cc = cid - 8;
        async_copy16(e_lo + (size_t)(bm * 128 + cc * 16 + lrow) * GD_DIM + kt + lcol,
                     &Al[cc * 512]);
      } else if (cid < 20) {
        int cc = cid - 16;
        async_copy16(wdh + (size_t)(bn * 64 + cc * 16 + lrow) * GD_DIM + kt + lcol,
                     &Dh[cc * 512]);
      } else if (cid < 24) {
        int cc = cid - 20;
        async_copy16(wdl + (size_t)(bn * 64 + cc * 16 + lrow) * GD_DIM + kt + lcol,
                     &Dl[cc * 512]);
      } else if (cid < 28) {
        int cc = cid - 24;
        async_copy16(wuh + (size_t)(bn * 64 + cc * 16 + lrow) * GD_DIM + kt + lcol,
                     &Uh[cc * 512]);
      } else {
        int cc = cid - 28;
        async_copy16(wul + (size_t)(bn * 64 + cc * 16 + lrow) * GD_DIM + kt + lcol,
                     &Ul[cc * 512]);
      }
    }
    __syncthreads();
    bf16x8 fah[4], fal[4], fdh[2], fdl[2], fuh[2], ful[2];
#pragma unroll
    for (int m = 0; m < 4; ++m) {
      int off = (wr * 64 + m * 16 + (lane & 15)) * 32 + (lane >> 4) * 8;
      fah[m] = *(const bf16x8*)&Ah[off];
      fal[m] = *(const bf16x8*)&Al[off];
    }
#pragma unroll
    for (int n = 0; n < 2; ++n) {
      int off = (wc * 32 + n * 16 + (lane & 15)) * 32 + (lane >> 4) * 8;
      fdh[n] = *(const bf16x8*)&Dh[off];
      fdl[n] = *(const bf16x8*)&Dl[off];
      fuh[n] = *(const bf16x8*)&Uh[off];
      ful[n] = *(const bf16x8*)&Ul[off];
    }
#pragma unroll
    for (int m = 0; m < 4; ++m)
#pragma unroll
      for (int n = 0; n < 2; ++n) {
        accD[m][n] = __builtin_amdgcn_mfma_f32_16x16x32_bf16(fah[m], fdh[n], accD[m][n], 0, 0, 0);
        accD[m][n] = __builtin_amdgcn_mfma_f32_16x16x32_bf16(fah[m], fdl[n], accD[m][n], 0, 0, 0);
        accD[m][n] = __builtin_amdgcn_mfma_f32_16x16x32_bf16(fal[m], fdh[n], accD[m][n], 0, 0, 0);
        accU[m][n] = __builtin_amdgcn_mfma_f32_16x16x32_bf16(fah[m], fuh[n], accU[m][n], 0, 0, 0);
        accU[m][n] = __builtin_amdgcn_mfma_f32_16x16x32_bf16(fah[m], ful[n], accU[m][n], 0, 0, 0);
        accU[m][n] = __builtin_amdgcn_mfma_f32_16x16x32_bf16(fal[m], fuh[n], accU[m][n], 0, 0, 0);
      }
  }
  float sc = scale_p[0];
#pragma unroll
  for (int m = 0; m < 4; ++m)
#pragma unroll
    for (int j = 0; j < 4; ++j) {
      int token = bm * 128 + wr * 64 + m * 16 + (lane >> 4) * 4 + j;
      float rr = r[token];
#pragma unroll
      for (int n = 0; n < 2; ++n) {
        int d = bn * 64 + wc * 32 + n * 16 + (lane & 15);
        float xn = x[(size_t)token * D_DIM + d] * rr * nw[d];
        out[(size_t)token * D_DIM + d] = tanhf(accD[m][n][j]) * xn * accU[m][n][j] * sc;
      }
    }
}

extern "C" void kernel_launch(void* const* d_in, const int* in_sizes, int n_in,
                              void* d_out, int out_size, void* d_ws, size_t ws_size,
                              hipStream_t stream) {
  const float* x       = (const float*)d_in[0];
  const float* Wc      = (const float*)d_in[1];
  const float* temp    = (const float*)d_in[2];
  const float* genes   = (const float*)d_in[3];
  const float* Wd      = (const float*)d_in[4];
  const float* Wu      = (const float*)d_in[5];
  const float* nw      = (const float*)d_in[6];
  const float* scale_p = (const float*)d_in[7];

  char* ws = (char*)d_ws;
  float* r_buf          = (float*)ws;                                   // 32 KB (64 KB reserved)
  unsigned short* xn_bf = (unsigned short*)(ws + 65536);                // 32 MB (free after k3)
  unsigned short* wc_bf = (unsigned short*)(ws + 65536 + (size_t)M_TOK * D_DIM * 2);   // 16 MB
  char* p = ws + 65536 + (size_t)M_TOK * D_DIM * 2 + (size_t)G_GENES * D_DIM * 2;
  int* cand    = (int*)p;                       p += (size_t)M_TOK * NCAND * 4;
  p += (size_t)M_TOK * NCAND * 8;               // (former cval slot, unused)
  unsigned short* e_hi = (unsigned short*)p;    p += (size_t)M_TOK * GD_DIM * 2;
  unsigned short* e_lo = (unsigned short*)p;

  // Wd/Wu bf16 hi/lo splits live in the xn_bf region (dead after k3): 4 x 1 MB
  unsigned short* wdh = (unsigned short*)(ws + 65536);
  unsigned short* wdl = wdh + (size_t)D_DIM * GD_DIM;
  unsigned short* wuh = wdl + (size_t)D_DIM * GD_DIM;
  unsigned short* wul = wuh + (size_t)D_DIM * GD_DIM;
  // fp64 partials also in the dead xn_bf region, after the 4 MB of splits:
  // 8192 x 8 x 40 x 8B = 21 MB (region holds 32 MB total)
  double* part = (double*)(ws + 65536 + 4ull * D_DIM * GD_DIM * 2);

  unsigned short* logits_bf = (unsigned short*)d_out;  // 33.5M bf16 == 64 MB == d_out

  k1_rmsnorm<<<dim3(M_TOK), dim3(256), 0, stream>>>(x, nw, r_buf, xn_bf);
  k2_cvt<<<dim3((G_GENES * D_DIM) / (256 * 8)), dim3(256), 0, stream>>>(Wc, wc_bf);
  k3_gemm_logits<<<dim3((M_TOK / 256) * (G_GENES / 256)), dim3(512), 0, stream>>>(xn_bf, wc_bf, logits_bf);
  k4_topk<<<dim3(M_TOK / 4), dim3(256), 0, stream>>>(logits_bf, cand);
  k2b_split<<<dim3((D_DIM * GD_DIM) / (256 * 4), 2), dim3(256), 0, stream>>>(Wd, Wu, wdh, wdl, wuh, wul);
  k5a_partial<<<dim3(M_TOK), dim3(256), 0, stream>>>(x, r_buf, nw, Wc, cand, part);
  k6_express<<<dim3(M_TOK), dim3(256), 0, stream>>>(part, cand, genes, temp, e_hi, e_lo);
  k7_mfma<<<dim3(D_DIM / 64, M_TOK / 128), dim3(256), 0, stream>>>(e_hi, e_lo, wdh, wdl, wuh, wul,
                                                                   x, r_buf, nw, scale_p, (float*)d_out);
}

// Round 9
// 453.775 us; speedup vs baseline: 2.0434x; 1.1540x over previous
//
#include <hip/hip_runtime.h>
#include <math.h>

#define M_TOK 8192
#define D_DIM 2048
#define G_GENES 4096
#define GD_DIM 256
#define KSEL 32
#define NCAND 40
#define NSLICE 8

typedef float f32x4 __attribute__((ext_vector_type(4)));
typedef short bf16x8 __attribute__((ext_vector_type(8)));

__device__ __forceinline__ void async_copy16(const void* g, void* lds) {
  __builtin_amdgcn_global_load_lds((const __attribute__((address_space(1))) void*)g,
                                   (__attribute__((address_space(3))) void*)lds, 16, 0, 0);
}

__device__ __forceinline__ unsigned short f2bf(float f) {
  unsigned int u = __float_as_uint(f);
  unsigned int r = (u + 0x7fffu + ((u >> 16) & 1u)) >> 16;
  return (unsigned short)r;
}
__device__ __forceinline__ float bf2f(unsigned short h) {
  return __uint_as_float(((unsigned int)h) << 16);
}

// ---------------- K1: RMSNorm -> r[t], xn_bf16 ----------------
__global__ __launch_bounds__(256) void k1_rmsnorm(const float* __restrict__ x,
                                                  const float* __restrict__ nw,
                                                  float* __restrict__ r_out,
                                                  unsigned short* __restrict__ xn_bf) {
  int t = blockIdx.x, tid = threadIdx.x;
  const float4* xr = (const float4*)(x + (size_t)t * D_DIM);
  float4 a = xr[tid], b = xr[tid + 256];
  double ss = (double)a.x*a.x + (double)a.y*a.y + (double)a.z*a.z + (double)a.w*a.w
            + (double)b.x*b.x + (double)b.y*b.y + (double)b.z*b.z + (double)b.w*b.w;
  for (int off = 32; off; off >>= 1) ss += __shfl_down(ss, off);
  __shared__ double sred[4];
  __shared__ float rshare;
  int lane = tid & 63, wv = tid >> 6;
  if (lane == 0) sred[wv] = ss;
  __syncthreads();
  if (tid == 0) {
    double tot = sred[0] + sred[1] + sred[2] + sred[3];
    float r = (float)(1.0 / sqrt(tot / (double)D_DIM + 1.1920928955078125e-7));
    rshare = r; r_out[t] = r;
  }
  __syncthreads();
  float r = rshare;
  const float4* nw4 = (const float4*)nw;
  float4 na = nw4[tid], nb = nw4[tid + 256];
  ushort4 oa, ob;
  oa.x = f2bf(a.x * r * na.x); oa.y = f2bf(a.y * r * na.y);
  oa.z = f2bf(a.z * r * na.z); oa.w = f2bf(a.w * r * na.w);
  ob.x = f2bf(b.x * r * nb.x); ob.y = f2bf(b.y * r * nb.y);
  ob.z = f2bf(b.z * r * nb.z); ob.w = f2bf(b.w * r * nb.w);
  ushort4* o4 = (ushort4*)(xn_bf + (size_t)t * D_DIM);
  o4[tid] = oa; o4[tid + 256] = ob;
}

// ---------------- K2: Wc fp32 -> bf16 ----------------
__global__ __launch_bounds__(256) void k2_cvt(const float* __restrict__ w,
                                              unsigned short* __restrict__ wb) {
  size_t i = (size_t)blockIdx.x * 256 + threadIdx.x;   // handles 8 elements
  const float4* w4 = (const float4*)w;
  float4 a = w4[2*i], b = w4[2*i+1];
  ushort4 oa, ob;
  oa.x = f2bf(a.x); oa.y = f2bf(a.y); oa.z = f2bf(a.z); oa.w = f2bf(a.w);
  ob.x = f2bf(b.x); ob.y = f2bf(b.y); ob.z = f2bf(b.z); ob.w = f2bf(b.w);
  ((ushort4*)wb)[2*i] = oa; ((ushort4*)wb)[2*i+1] = ob;
}

// ---------------- K2b: split Wd/Wu into bf16 hi+lo ----------------
__global__ __launch_bounds__(256) void k2b_split(const float* __restrict__ wd,
                                                 const float* __restrict__ wu,
                                                 unsigned short* __restrict__ wdh,
                                                 unsigned short* __restrict__ wdl,
                                                 unsigned short* __restrict__ wuh,
                                                 unsigned short* __restrict__ wul) {
  const float* src = blockIdx.y ? wu : wd;
  unsigned short* dh = blockIdx.y ? wuh : wdh;
  unsigned short* dl = blockIdx.y ? wul : wdl;
  size_t i = (size_t)blockIdx.x * 256 + threadIdx.x;   // float4 index
  float4 v = ((const float4*)src)[i];
  ushort4 h, l;
  h.x = f2bf(v.x); l.x = f2bf(v.x - bf2f(h.x));
  h.y = f2bf(v.y); l.y = f2bf(v.y - bf2f(h.y));
  h.z = f2bf(v.z); l.z = f2bf(v.z - bf2f(h.z));
  h.w = f2bf(v.w); l.w = f2bf(v.w - bf2f(h.w));
  ((ushort4*)dh)[i] = h;
  ((ushort4*)dl)[i] = l;
}

// ---------------- K3: logits GEMM, 256x256 tile, 8-wave, phase-split + counted vmcnt ----------------
__global__ __launch_bounds__(512, 1) void k3_gemm_logits(const unsigned short* __restrict__ A,
                                                         const unsigned short* __restrict__ B,
                                                         unsigned short* __restrict__ C) {
  __shared__ unsigned short As[4][256 * 32];
  __shared__ unsigned short Bs[4][256 * 32];
  const int tid = threadIdx.x;
  const int lane = tid & 63, wv = tid >> 6;
  const int wm = wv >> 2, wn = wv & 3;       // wave tile: 128(M) x 64(N)
  int lin = blockIdx.x;
  int swz = (lin & 7) * 64 + (lin >> 3);
  const int bm = swz & 31, bn = swz >> 5;

  const int grow = lane >> 2;                          // 0..15 within 16-row issue
  const int gslot = (lane & 3) ^ ((lane >> 3) & 3);    // pre-swizzled global slot
  const unsigned short* agp = A + (size_t)(bm * 256 + wv * 32 + grow) * D_DIM + gslot * 8;
  const unsigned short* bgp = B + (size_t)(bn * 256 + wv * 32 + grow) * D_DIM + gslot * 8;
  const int fr = lane & 15;
  const int sw8 = (((lane >> 4) ^ ((lane >> 1) & 3))) * 8;  // swizzled 16B slot * 8 ushorts

  f32x4 acc[8][4];
#pragma unroll
  for (int m = 0; m < 8; ++m)
#pragma unroll
    for (int n = 0; n < 4; ++n) acc[m][n] = (f32x4){0.f, 0.f, 0.f, 0.f};

#define STAGE_A3(t_) { const int b_ = (t_) & 3; const int kt_ = (t_) * 32;          \
    async_copy16(agp + kt_,              &As[b_][(wv * 32) * 32]);                   \
    async_copy16(agp + kt_ + 16 * D_DIM, &As[b_][(wv * 32 + 16) * 32]); }
#define STAGE_B3(t_) { const int b_ = (t_) & 3; const int kt_ = (t_) * 32;          \
    async_copy16(bgp + kt_,              &Bs[b_][(wv * 32) * 32]);                   \
    async_copy16(bgp + kt_ + 16 * D_DIM, &Bs[b_][(wv * 32 + 16) * 32]); }

  STAGE_A3(0); STAGE_B3(0);
  STAGE_A3(1); STAGE_B3(1);
  STAGE_A3(2); STAGE_B3(2);
  asm volatile("s_waitcnt vmcnt(8)" ::: "memory");
  __builtin_amdgcn_s_barrier();

#pragma unroll 1
  for (int t = 0; t < 64; ++t) {
    const int c = t & 3;
    const unsigned short* as = As[c];
    const unsigned short* bs = Bs[c];
    bf16x8 fa[4], fb[4];
#pragma unroll
    for (int n = 0; n < 4; ++n)
      fb[n] = *(const bf16x8*)&bs[(wn * 64 + n * 16 + fr) * 32 + sw8];
#pragma unroll
    for (int m = 0; m < 4; ++m)
      fa[m] = *(const bf16x8*)&as[(wm * 128 + m * 16 + fr) * 32 + sw8];
    if (t + 3 < 64) STAGE_A3(t + 3);
    __builtin_amdgcn_s_barrier();
    asm volatile("s_waitcnt lgkmcnt(0)" ::: "memory");
    __builtin_amdgcn_sched_barrier(0);
    __builtin_amdgcn_s_setprio(1);
#pragma unroll
    for (int m = 0; m < 4; ++m)
#pragma unroll
      for (int n = 0; n < 4; ++n)
        acc[m][n] = __builtin_amdgcn_mfma_f32_16x16x32_bf16(fa[m], fb[n], acc[m][n], 0, 0, 0);
    __builtin_amdgcn_s_setprio(0);
    __builtin_amdgcn_s_barrier();
#pragma unroll
    for (int m = 0; m < 4; ++m)
      fa[m] = *(const bf16x8*)&as[(wm * 128 + 64 + m * 16 + fr) * 32 + sw8];
    if (t + 3 < 64) STAGE_B3(t + 3);
    __builtin_amdgcn_s_barrier();
    asm volatile("s_waitcnt lgkmcnt(0)" ::: "memory");
    __builtin_amdgcn_sched_barrier(0);
    __builtin_amdgcn_s_setprio(1);
#pragma unroll
    for (int m = 0; m < 4; ++m)
#pragma unroll
      for (int n = 0; n < 4; ++n)
        acc[m + 4][n] = __builtin_amdgcn_mfma_f32_16x16x32_bf16(fa[m], fb[n], acc[m + 4][n], 0, 0, 0);
    __builtin_amdgcn_s_setprio(0);
    if (t <= 60)      { asm volatile("s_waitcnt vmcnt(8)" ::: "memory"); }
    else if (t == 61) { asm volatile("s_waitcnt vmcnt(4)" ::: "memory"); }
    else if (t == 62) { asm volatile("s_waitcnt vmcnt(0)" ::: "memory"); }
    __builtin_amdgcn_s_barrier();
  }
#undef STAGE_A3
#undef STAGE_B3

#pragma unroll
  for (int m = 0; m < 8; ++m)
#pragma unroll
    for (int n = 0; n < 4; ++n)
#pragma unroll
      for (int j = 0; j < 4; ++j) {
        int row = bm * 256 + wm * 128 + m * 16 + (lane >> 4) * 4 + j;
        int col = bn * 256 + wn * 64 + n * 16 + fr;
        C[(size_t)row * G_GENES + col] = f2bf(acc[m][n][j]);
      }
}

// ---------------- K4: per-token top-40 via 16-bit radix threshold search ----------------
__global__ __launch_bounds__(256) void k4_topk(const unsigned short* __restrict__ L,
                                               int* __restrict__ cand) {
  int wv = threadIdx.x >> 6, lane = threadIdx.x & 63;
  int t = blockIdx.x * 4 + wv;
  const unsigned short* lp = L + (size_t)t * G_GENES;
  unsigned kp[32];
#pragma unroll
  for (int i = 0; i < 8; ++i) {
    uint4 raw = *(const uint4*)(lp + i * 512 + lane * 8);
    unsigned rr[4] = {raw.x, raw.y, raw.z, raw.w};
#pragma unroll
    for (int q = 0; q < 4; ++q) {
      unsigned r = rr[q];
      unsigned s = (r >> 15) & 0x00010001u;
      unsigned xm = 0x80008000u | (s * 0x7FFFu);   // per-half: sign? 0xFFFF : 0x8000
      kp[i * 4 + q] = r ^ xm;
    }
  }
  unsigned lo = 0, hi = 65536;
  while (hi - lo > 1u) {
    unsigned mid = (lo + hi) >> 1;
    int c = 0;
#pragma unroll
    for (int q = 0; q < 32; ++q) {
      c += __popcll(__ballot((kp[q] & 0xFFFFu) >= mid));
      c += __popcll(__ballot((kp[q] >> 16) >= mid));
    }
    if (c >= NCAND) lo = mid; else hi = mid;
  }
  const unsigned T = lo;
  unsigned long long below = (1ull << lane) - 1ull;
  int* outp = cand + (size_t)t * NCAND;
  int cnt = 0;
#pragma unroll
  for (int q = 0; q < 32; ++q) {
#pragma unroll
    for (int h = 0; h < 2; ++h) {
      unsigned key = h ? (kp[q] >> 16) : (kp[q] & 0xFFFFu);
      bool pred = key > T;
      unsigned long long m = __ballot(pred);
      if (pred) {
        int pos = cnt + (int)__popcll(m & below);
        outp[pos] = (q >> 2) * 512 + lane * 8 + (q & 3) * 2 + h;
      }
      cnt += (int)__popcll(m);
    }
  }
#pragma unroll 1
  for (int q = 0; q < 32 && cnt < NCAND; ++q) {
#pragma unroll
    for (int h = 0; h < 2; ++h) {
      unsigned key = h ? (kp[q] >> 16) : (kp[q] & 0xFFFFu);
      bool pred = key == T;
      unsigned long long m = __ballot(pred);
      if (pred) {
        int pos = cnt + (int)__popcll(m & below);
        if (pos < NCAND)
          outp[pos] = (q >> 2) * 512 + lane * 8 + (q & 3) * 2 + h;
      }
      cnt += (int)__popcll(m);
    }
  }
}

// ---------------- K5a: fp64 partial rescore, D-sliced, compress-tree reduce ----------------
__global__ __launch_bounds__(256) void k5a_partial(const float* __restrict__ x,
                                                   const float* __restrict__ r,
                                                   const float* __restrict__ nw,
                                                   const float* __restrict__ Wc,
                                                   const int* __restrict__ cand,
                                                   double* __restrict__ part) {
  int bid = blockIdx.x;
  int slice = bid & 7;
  int group = bid >> 3;
  int wv = threadIdx.x >> 6, lane = threadIdx.x & 63;
  const int dbase = slice * 256;
  float4 nv = *(const float4*)(nw + dbase + lane * 4);
  bool b0 = (lane & 1) != 0, b1 = (lane & 2) != 0, b2 = (lane & 4) != 0;
#pragma unroll 1
  for (int tt = 0; tt < 2; ++tt) {
    int t = group * 8 + wv * 2 + tt;
    float rr = r[t];
    float4 xv = *(const float4*)(x + (size_t)t * D_DIM + dbase + lane * 4);
    float4 xl;
    xl.x = xv.x * rr * nv.x;
    xl.y = xv.y * rr * nv.y;
    xl.z = xv.z * rr * nv.z;
    xl.w = xv.w * rr * nv.w;
    int myg = cand[t * NCAND + (lane < NCAND ? lane : 0)];
    double* outp = part + ((size_t)t * NSLICE + slice) * NCAND;
#pragma unroll 1
    for (int j0 = 0; j0 < NCAND; j0 += 8) {
      float4 w[8];
#pragma unroll
      for (int c = 0; c < 8; ++c) {
        int g = __shfl(myg, j0 + c);
        w[c] = *(const float4*)(Wc + (size_t)g * D_DIM + dbase + lane * 4);
      }
      double s[8];
#pragma unroll
      for (int c = 0; c < 8; ++c)
        s[c] = ((double)xl.x * (double)w[c].x + (double)xl.y * (double)w[c].y)
             + ((double)xl.z * (double)w[c].z + (double)xl.w * (double)w[c].w);
      // stage A (bit0): 8 -> 4 regs
      double u01 = b0 ? s[1] : s[0], t01 = b0 ? s[0] : s[1];
      double u23 = b0 ? s[3] : s[2], t23 = b0 ? s[2] : s[3];
      double u45 = b0 ? s[5] : s[4], t45 = b0 ? s[4] : s[5];
      double u67 = b0 ? s[7] : s[6], t67 = b0 ? s[6] : s[7];
      u01 += __shfl_xor(t01, 1);
      u23 += __shfl_xor(t23, 1);
      u45 += __shfl_xor(t45, 1);
      u67 += __shfl_xor(t67, 1);
      // stage B (bit1): 4 -> 2 regs
      double v03 = b1 ? u23 : u01, t03 = b1 ? u01 : u23;
      double v47 = b1 ? u67 : u45, t47 = b1 ? u45 : u67;
      v03 += __shfl_xor(t03, 2);
      v47 += __shfl_xor(t47, 2);
      // stage C (bit2): 2 -> 1 reg; lane l holds candidate (l&7) group-sum
      double wsum = b2 ? v47 : v03, t07 = b2 ? v03 : v47;
      wsum += __shfl_xor(t07, 4);
      // stages D-F: reduce across 8-lane groups
      wsum += __shfl_xor(wsum, 8);
      wsum += __shfl_xor(wsum, 16);
      wsum += __shfl_xor(wsum, 32);
      if (lane < 8) outp[j0 + lane] = wsum;
    }
  }
}

// ---------------- K6: sum partials, select top-32, softmax, combine ----------------
__global__ __launch_bounds__(256) void k6_express(const double* __restrict__ part,
                                                  const int* __restrict__ cand,
                                                  const float* __restrict__ genes,
                                                  const float* __restrict__ temp,
                                                  unsigned short* __restrict__ e_hi,
                                                  unsigned short* __restrict__ e_lo) {
  int t = blockIdx.x, tid = threadIdx.x;
  __shared__ double sval[NCAND];
  __shared__ int sidx[NCAND];
  __shared__ float sw[NCAND];
  float tclamp = fmaxf(temp[0], 0.1f);
  if (tid < NCAND) {
    const double* pp = part + (size_t)t * NSLICE * NCAND + tid;
    double v = 0.0;
#pragma unroll
    for (int s = 0; s < NSLICE; ++s) v += pp[s * NCAND];
    sval[tid] = v / (double)tclamp;
    sidx[tid] = cand[(size_t)t * NCAND + tid];
  }
  __syncthreads();
  if (tid < 64) {
    double v = (tid < NCAND) ? sval[tid] : -1.0e300;
    int gi = (tid < NCAND) ? sidx[tid] : 0x7fffffff;
    int rank = 0;
    for (int j = 0; j < NCAND; ++j) {
      double vj = sval[j]; int gj = sidx[j];
      if (vj > v || (vj == v && gj < gi)) rank++;
    }
    bool sel = (tid < NCAND) && (rank < KSEL);
    double vs = sel ? v : -1.0e300;
    double mx = vs;
    for (int off = 32; off; off >>= 1) { double o = __shfl_xor(mx, off); mx = fmax(mx, o); }
    double e = sel ? exp(v - mx) : 0.0;
    double ssum = e;
    for (int off = 32; off; off >>= 1) ssum += __shfl_xor(ssum, off);
    if (tid < NCAND) sw[tid] = (float)(e / ssum);
  }
  __syncthreads();
  float a0 = 0.f, a1 = 0.f, a2 = 0.f, a3 = 0.f;
#pragma unroll
  for (int k = 0; k < NCAND; k += 4) {
    a0 += sw[k]     * genes[(size_t)sidx[k]     * GD_DIM + tid];
    a1 += sw[k + 1] * genes[(size_t)sidx[k + 1] * GD_DIM + tid];
    a2 += sw[k + 2] * genes[(size_t)sidx[k + 2] * GD_DIM + tid];
    a3 += sw[k + 3] * genes[(size_t)sidx[k + 3] * GD_DIM + tid];
  }
  float acc = (a0 + a1) + (a2 + a3);
  unsigned short h = f2bf(acc);
  unsigned short l = f2bf(acc - bf2f(h));
  e_hi[(size_t)t * GD_DIM + tid] = h;
  e_lo[(size_t)t * GD_DIM + tid] = l;
}

// ---------------- K7: bf16-split MFMA down/up GEMM, k3-style schedule ----------------
// Tile 128(M) x 128(N), K=256, BK=32 (8 K-tiles), ring-3 LDS (144 KB), 8 waves
// (2M x 4N, wave = 64x32). Per K-tile: phase1 = 24 D-MFMAs, phase2 = 24 U-MFMAs
// (A-frags reused). Counted vmcnt(6); both-sides XOR swizzle as in k3.
// Accumulation order per element identical to previous k7 (hh, hl, lh; kt asc).
__global__ __launch_bounds__(512, 1) void k7_mfma(const unsigned short* __restrict__ e_hi,
                                                  const unsigned short* __restrict__ e_lo,
                                                  const unsigned short* __restrict__ wdh,
                                                  const unsigned short* __restrict__ wdl,
                                                  const unsigned short* __restrict__ wuh,
                                                  const unsigned short* __restrict__ wul,
                                                  const float* __restrict__ x,
                                                  const float* __restrict__ r,
                                                  const float* __restrict__ nw,
                                                  const float* __restrict__ scale_p,
                                                  float* __restrict__ out) {
  __shared__ unsigned short L[3][6][128 * 32];   // 144 KB: comp 0=Ah 1=Al 2=Dh 3=Dl 4=Uh 5=Ul
  const int tid = threadIdx.x;
  const int lane = tid & 63, wv = tid >> 6;
  const int wm = wv >> 2, wn = wv & 3;           // wave tile 64(M) x 32(N)
  int lin = blockIdx.x;
  int swz = (lin & 7) * 128 + (lin >> 3);        // bijective XCD swizzle (1024 % 8 == 0)
  const int bm = swz & 63, bn = swz >> 6;

  const int grow = lane >> 2;
  const int gslot = (lane & 3) ^ ((lane >> 3) & 3);
  const int goff = gslot * 8;
  const unsigned short* ehp = e_hi + (size_t)(bm * 128 + wv * 16 + grow) * GD_DIM + goff;
  const unsigned short* elp = e_lo + (size_t)(bm * 128 + wv * 16 + grow) * GD_DIM + goff;
  const unsigned short* dhp = wdh + (size_t)(bn * 128 + wv * 16 + grow) * GD_DIM + goff;
  const unsigned short* dlp = wdl + (size_t)(bn * 128 + wv * 16 + grow) * GD_DIM + goff;
  const unsigned short* uhp = wuh + (size_t)(bn * 128 + wv * 16 + grow) * GD_DIM + goff;
  const unsigned short* ulp = wul + (size_t)(bn * 128 + wv * 16 + grow) * GD_DIM + goff;
  const int ldst = (wv * 16) * 32;               // this wave's 16-row chunk (lds elems)

  const int fr = lane & 15;
  const int sw8 = ((lane >> 4) ^ ((lane >> 1) & 3)) * 8;

  f32x4 accD[4][2], accU[4][2];
#pragma unroll
  for (int m = 0; m < 4; ++m)
#pragma unroll
    for (int n = 0; n < 2; ++n) {
      accD[m][n] = (f32x4){0.f, 0.f, 0.f, 0.f};
      accU[m][n] = (f32x4){0.f, 0.f, 0.f, 0.f};
    }

#define STAGE7(t_) if ((t_) < 8) { const int b_ = (t_) % 3; const int kt_ = (t_) * 32; \
    async_copy16(ehp + kt_, &L[b_][0][ldst]); \
    async_copy16(elp + kt_, &L[b_][1][ldst]); \
    async_copy16(dhp + kt_, &L[b_][2][ldst]); \
    async_copy16(dlp + kt_, &L[b_][3][ldst]); \
    async_copy16(uhp + kt_, &L[b_][4][ldst]); \
    async_copy16(ulp + kt_, &L[b_][5][ldst]); }

  STAGE7(0); STAGE7(1);
  asm volatile("s_waitcnt vmcnt(6)" ::: "memory");
  __builtin_amdgcn_s_barrier();

#pragma unroll 1
  for (int t = 0; t < 8; ++t) {
    const int b = t % 3;
    bf16x8 fah[4], fal[4], fh[2], fl[2];
    // ---- phase 1: D-quadrant ----
#pragma unroll
    for (int m = 0; m < 4; ++m) {
      int off = (wm * 64 + m * 16 + fr) * 32 + sw8;
      fah[m] = *(const bf16x8*)&L[b][0][off];
      fal[m] = *(const bf16x8*)&L[b][1][off];
    }
#pragma unroll
    for (int n = 0; n < 2; ++n) {
      int off = (wn * 32 + n * 16 + fr) * 32 + sw8;
      fh[n] = *(const bf16x8*)&L[b][2][off];
      fl[n] = *(const bf16x8*)&L[b][3][off];
    }
    STAGE7(t + 2);
    __builtin_amdgcn_s_barrier();
    asm volatile("s_waitcnt lgkmcnt(0)" ::: "memory");
    __builtin_amdgcn_sched_barrier(0);
    __builtin_amdgcn_s_setprio(1);
#pragma unroll
    for (int m = 0; m < 4; ++m)
#pragma unroll
      for (int n = 0; n < 2; ++n) {
        accD[m][n] = __builtin_amdgcn_mfma_f32_16x16x32_bf16(fah[m], fh[n], accD[m][n], 0, 0, 0);
        accD[m][n] = __builtin_amdgcn_mfma_f32_16x16x32_bf16(fah[m], fl[n], accD[m][n], 0, 0, 0);
        accD[m][n] = __builtin_amdgcn_mfma_f32_16x16x32_bf16(fal[m], fh[n], accD[m][n], 0, 0, 0);
      }
    __builtin_amdgcn_s_setprio(0);
    __builtin_amdgcn_s_barrier();
    // ---- phase 2: U-quadrant (fah/fal reused) ----
#pragma unroll
    for (int n = 0; n < 2; ++n) {
      int off = (wn * 32 + n * 16 + fr) * 32 + sw8;
      fh[n] = *(const bf16x8*)&L[b][4][off];
      fl[n] = *(const bf16x8*)&L[b][5][off];
    }
    __builtin_amdgcn_s_barrier();
    asm volatile("s_waitcnt lgkmcnt(0)" ::: "memory");
    __builtin_amdgcn_sched_barrier(0);
    __builtin_amdgcn_s_setprio(1);
#pragma unroll
    for (int m = 0; m < 4; ++m)
#pragma unroll
      for (int n = 0; n < 2; ++n) {
        accU[m][n] = __builtin_amdgcn_mfma_f32_16x16x32_bf16(fah[m], fh[n], accU[m][n], 0, 0, 0);
        accU[m][n] = __builtin_amdgcn_mfma_f32_16x16x32_bf16(fah[m], fl[n], accU[m][n], 0, 0, 0);
        accU[m][n] = __builtin_amdgcn_mfma_f32_16x16x32_bf16(fal[m], fh[n], accU[m][n], 0, 0, 0);
      }
    __builtin_amdgcn_s_setprio(0);
    if (t <= 5)      { asm volatile("s_waitcnt vmcnt(6)" ::: "memory"); }
    else if (t == 6) { asm volatile("s_waitcnt vmcnt(0)" ::: "memory"); }
    __builtin_amdgcn_s_barrier();
  }
#undef STAGE7

  float sc = scale_p[0];
#pragma unroll
  for (int m = 0; m < 4; ++m)
#pragma unroll
    for (int j = 0; j < 4; ++j) {
      int token = bm * 128 + wm * 64 + m * 16 + (lane >> 4) * 4 + j;
      float rr = r[token];
#pragma unroll
      for (int n = 0; n < 2; ++n) {
        int d = bn * 128 + wn * 32 + n * 16 + fr;
        float xn = x[(size_t)token * D_DIM + d] * rr * nw[d];
        out[(size_t)token * D_DIM + d] = tanhf(accD[m][n][j]) * xn * accU[m][n][j] * sc;
      }
    }
}

extern "C" void kernel_launch(void* const* d_in, const int* in_sizes, int n_in,
                              void* d_out, int out_size, void* d_ws, size_t ws_size,
                              hipStream_t stream) {
  const float* x       = (const float*)d_in[0];
  const float* Wc      = (const float*)d_in[1];
  const float* temp    = (const float*)d_in[2];
  const float* genes   = (const float*)d_in[3];
  const float* Wd      = (const float*)d_in[4];
  const float* Wu      = (const float*)d_in[5];
  const float* nw      = (const float*)d_in[6];
  const float* scale_p = (const float*)d_in[7];

  char* ws = (char*)d_ws;
  float* r_buf          = (float*)ws;                                   // 32 KB (64 KB reserved)
  unsigned short* xn_bf = (unsigned short*)(ws + 65536);                // 32 MB (free after k3)
  unsigned short* wc_bf = (unsigned short*)(ws + 65536 + (size_t)M_TOK * D_DIM * 2);   // 16 MB
  char* p = ws + 65536 + (size_t)M_TOK * D_DIM * 2 + (size_t)G_GENES * D_DIM * 2;
  int* cand    = (int*)p;                       p += (size_t)M_TOK * NCAND * 4;
  p += (size_t)M_TOK * NCAND * 8;               // (former cval slot, unused)
  unsigned short* e_hi = (unsigned short*)p;    p += (size_t)M_TOK * GD_DIM * 2;
  unsigned short* e_lo = (unsigned short*)p;

  // Wd/Wu bf16 hi/lo splits live in the xn_bf region (dead after k3): 4 x 1 MB
  unsigned short* wdh = (unsigned short*)(ws + 65536);
  unsigned short* wdl = wdh + (size_t)D_DIM * GD_DIM;
  unsigned short* wuh = wdl + (size_t)D_DIM * GD_DIM;
  unsigned short* wul = wuh + (size_t)D_DIM * GD_DIM;
  // fp64 partials also in the dead xn_bf region, after the 4 MB of splits:
  double* part = (double*)(ws + 65536 + 4ull * D_DIM * GD_DIM * 2);

  unsigned short* logits_bf = (unsigned short*)d_out;  // 33.5M bf16 == 64 MB == d_out

  k1_rmsnorm<<<dim3(M_TOK), dim3(256), 0, stream>>>(x, nw, r_buf, xn_bf);
  k2_cvt<<<dim3((G_GENES * D_DIM) / (256 * 8)), dim3(256), 0, stream>>>(Wc, wc_bf);
  k3_gemm_logits<<<dim3((M_TOK / 256) * (G_GENES / 256)), dim3(512), 0, stream>>>(xn_bf, wc_bf, logits_bf);
  k4_topk<<<dim3(M_TOK / 4), dim3(256), 0, stream>>>(logits_bf, cand);
  k2b_split<<<dim3((D_DIM * GD_DIM) / (256 * 4), 2), dim3(256), 0, stream>>>(Wd, Wu, wdh, wdl, wuh, wul);
  k5a_partial<<<dim3(M_TOK), dim3(256), 0, stream>>>(x, r_buf, nw, Wc, cand, part);
  k6_express<<<dim3(M_TOK), dim3(256), 0, stream>>>(part, cand, genes, temp, e_hi, e_lo);
  k7_mfma<<<dim3((M_TOK / 128) * (D_DIM / 128)), dim3(512), 0, stream>>>(e_hi, e_lo, wdh, wdl, wuh, wul,
                                                                         x, r_buf, nw, scale_p, (float*)d_out);
}